// Round 2
// baseline (2248.870 us; speedup 1.0000x reference)
//
#include <hip/hip_runtime.h>
#include <hip/hip_bf16.h>

// Problem constants
#define NN 25600      // D*H*W = 16*40*40
#define CC 96
#define NHh 4
#define HDd 24
#define LLl 27
#define PLl 50
#define SSLOT 2457600 // NN*CC floats per workspace slot
#define WSZ 248832    // 27*96*96 floats per conv weight tensor

// All tensors are float32 on device (per reference dtypes).
__device__ __forceinline__ float LD(const void* p, int i){
  return ((const float*)p)[i];
}

#define NEGINF (-3.0e38f)

// ---------------- K1: xt = x+1, LayerNorm over C, store XN[c][n] ----------------
__global__ void k_ln(const void* __restrict__ x, const void* __restrict__ nw,
                     const void* __restrict__ nb, float* __restrict__ XN){
  int n = blockIdx.x*256 + threadIdx.x;
  float s=0.f, ss=0.f;
  for(int c=0;c<CC;c++){ float v = LD(x, c*NN+n)+1.0f; s+=v; ss+=v*v; }
  float mu = s*(1.0f/CC);
  float var = ss*(1.0f/CC) - mu*mu;
  float inv = rsqrtf(var + 1e-5f);
  for(int c=0;c<CC;c++){
    float v = LD(x, c*NN+n)+1.0f;
    XN[c*NN+n] = (v-mu)*inv*LD(nw,c) + LD(nb,c);
  }
}

// ---------------- K2: qkvv = xn @ w_qkvv^T -> Q/K/VCA/VSA [h][n][d] ----------------
__global__ void k_qkvv(const float* __restrict__ XN, const void* __restrict__ w,
                       float* __restrict__ out){ // out = base of Q; slots s*SSLOT
  int n = blockIdx.x*256 + threadIdx.x;
  int o0 = blockIdx.y*16;
  const float* wp = (const float*)w;
  float acc[16];
  #pragma unroll
  for(int j=0;j<16;j++) acc[j]=0.f;
  for(int c=0;c<96;c+=4){
    float v0=XN[(c+0)*NN+n], v1=XN[(c+1)*NN+n], v2=XN[(c+2)*NN+n], v3=XN[(c+3)*NN+n];
    #pragma unroll
    for(int j=0;j<16;j++){
      const float4 wv = *reinterpret_cast<const float4*>(wp + (o0+j)*96 + c);
      acc[j] += wv.x*v0 + wv.y*v1 + wv.z*v2 + wv.w*v3;
    }
  }
  #pragma unroll
  for(int j=0;j<16;j++){
    int jj=o0+j, s=jj/96, rr=jj%96, h=rr/24, dd=rr%24;
    out[s*SSLOT + (h*NN+n)*24 + dd] = acc[j];
  }
}

// ---------------- K3: qn = l2(q), qs = (qn+qe)*softplus(T)*sls ----------------
__global__ void k_qs(const float* __restrict__ Q, const void* __restrict__ temp,
                     const void* __restrict__ sls, const void* __restrict__ qe,
                     float* __restrict__ QN, float* __restrict__ QS){
  int id = blockIdx.x*256 + threadIdx.x;
  if(id >= NHh*NN) return;
  int h = id/NN, n = id%NN;
  const float* qr = Q + (h*NN+n)*24;
  float qv[24]; float ss=0.f;
  #pragma unroll
  for(int d=0;d<24;d++){ qv[d]=qr[d]; ss+=qv[d]*qv[d]; }
  float inv = 1.0f/fmaxf(sqrtf(ss), 1e-12f);
  float t = LD(temp,h);
  float sp = log1pf(expf(t)) * LD(sls,0);
  #pragma unroll
  for(int d=0;d<24;d++){
    float qn = qv[d]*inv;
    QN[(h*NN+n)*24+d] = qn;
    QS[(h*NN+n)*24+d] = (qn + LD(qe, h*24+d))*sp;
  }
}

// ---------------- K4: xp2 = gelu(sr_w @ xn + sr_b), [c][n] ----------------
__global__ void k_sr(const float* __restrict__ XN, const void* __restrict__ w,
                     const void* __restrict__ b, float* __restrict__ XP2){
  int n = blockIdx.x*256 + threadIdx.x;
  int o0 = blockIdx.y*16;
  const float* wp = (const float*)w;
  float acc[16];
  #pragma unroll
  for(int j=0;j<16;j++) acc[j]=0.f;
  for(int c=0;c<96;c+=4){
    float v0=XN[(c+0)*NN+n], v1=XN[(c+1)*NN+n], v2=XN[(c+2)*NN+n], v3=XN[(c+3)*NN+n];
    #pragma unroll
    for(int j=0;j<16;j++){
      const float4 wv = *reinterpret_cast<const float4*>(wp + (o0+j)*96 + c);
      acc[j] += wv.x*v0 + wv.y*v1 + wv.z*v2 + wv.w*v3;
    }
  }
  #pragma unroll
  for(int j=0;j<16;j++){
    float y = acc[j] + LD(b, o0+j);
    y = 0.5f*y*(1.0f + erff(y*0.70710678118f));  // exact gelu
    XP2[(o0+j)*NN+n] = y;
  }
}

// ---------------- K5: 8x8x8 average pool over (X,Y,Z)=(40,40,16) view ----------------
__global__ void k_pool(const float* __restrict__ XP2, float* __restrict__ pooled){
  int bb = blockIdx.x;
  int c = bb % CC, p = bb / CC;
  int ph = p/10, pw = (p%10)/2, pd = p%2;
  float s = 0.f;
  for(int t=threadIdx.x; t<512; t+=64){
    int i=t>>6, j=(t>>3)&7, k=t&7;
    int m = (ph*8+i)*640 + (pw*8+j)*16 + (pd*8+k);
    s += XP2[c*NN+m];
  }
  #pragma unroll
  for(int off=32;off;off>>=1) s += __shfl_down(s, off);
  if(threadIdx.x==0) pooled[p*CC+c] = s*(1.0f/512.0f);
}

// ---------------- K5b: LN(pooled) then kv = xp @ w_kv^T -> KP/VP [h][p][d] ----------------
__global__ void k_lnkv(const float* __restrict__ pooled, const void* __restrict__ ew,
                       const void* __restrict__ eb, const void* __restrict__ wkv,
                       float* __restrict__ KP, float* __restrict__ VP){
  __shared__ float row[96], lnr[96], st[2];
  int p = blockIdx.x, t = threadIdx.x;
  if(t<96) row[t] = pooled[p*96+t];
  __syncthreads();
  if(t==0){
    float s=0.f, ss=0.f;
    for(int c=0;c<96;c++){ float v=row[c]; s+=v; ss+=v*v; }
    float mu=s*(1.0f/96.0f);
    float var=ss*(1.0f/96.0f)-mu*mu;
    st[0]=mu; st[1]=rsqrtf(var+1e-5f);
  }
  __syncthreads();
  if(t<96) lnr[t] = (row[t]-st[0])*st[1]*LD(ew,t) + LD(eb,t);
  __syncthreads();
  if(t<192){
    float a=0.f;
    for(int c=0;c<96;c++) a += LD(wkv, t*96+c)*lnr[c];
    int g=t/24, d=t%24;
    if(g<4) KP[(g*50+p)*24+d]=a;
    else    VP[((g-4)*50+p)*24+d]=a;
  }
}

// ---------------- K5c: k_pool l2-normalize over d ----------------
__global__ void k_kpn(const float* __restrict__ KP, float* __restrict__ KPN){
  int t = threadIdx.x;
  if(t>=200) return;
  const float* r = KP + t*24;
  float ss=0.f;
  #pragma unroll
  for(int d=0;d<24;d++) ss += r[d]*r[d];
  float inv = 1.0f/fmaxf(sqrtf(ss),1e-12f);
  #pragma unroll
  for(int d=0;d<24;d++) KPN[t*24+d] = r[d]*inv;
}

// ---------------- K6: cpb MLP -> tab[T][NH] ----------------
__global__ void k_tab(const void* __restrict__ rct, const void* __restrict__ w1,
                      const void* __restrict__ b1, const void* __restrict__ w2,
                      const void* __restrict__ b2, float* __restrict__ TAB){
  __shared__ float red[32];
  int tt = blockIdx.x, j = threadIdx.x;
  float r0=LD(rct,tt*3), r1=LD(rct,tt*3+1), r2=LD(rct,tt*3+2);
  float hj = r0*LD(w1,j*3) + r1*LD(w1,j*3+1) + r2*LD(w1,j*3+2) + LD(b1,j);
  hj = fmaxf(hj, 0.f);
  int lane=j&63, wid=j>>6;
  for(int h=0;h<4;h++){
    float v = hj*LD(w2, h*512+j);
    #pragma unroll
    for(int off=32;off;off>>=1) v += __shfl_down(v, off);
    if(lane==0) red[wid*4+h]=v;
  }
  __syncthreads();
  if(j<4){
    float s=0.f;
    for(int w=0;w<8;w++) s += red[w*4+j];
    TAB[tt*4+j] = s + LD(b2,j);
  }
}

// ---------------- K7: fused local+pool attention per (h,n), one wave/block ----------------
__global__ void k_attn(const float* __restrict__ QS, const float* __restrict__ QN,
                       const float* __restrict__ K,  const float* __restrict__ VSA,
                       const float* __restrict__ KPN,const float* __restrict__ VP,
                       const float* __restrict__ TAB,const int* __restrict__ rpi,
                       const void* __restrict__ rbl, const void* __restrict__ ltok,
                       const void* __restrict__ lbias, float* __restrict__ XSA){
  __shared__ float qsr[24], qnr[24], av[80], pv[80], lt[28];
  int bb = blockIdx.x;
  int h = bb % NHh, n = bb / NHh;
  int t = threadIdx.x;
  if(t<24){ qsr[t]=QS[(h*NN+n)*24+t]; qnr[t]=QN[(h*NN+n)*24+t]; }
  __syncthreads();
  int d0=n/1600, rr=n%1600, h0=rr/40, w0=rr%40;  // original (D,H,W) grid
  for(int key=t; key<77; key+=64){
    float a;
    if(key<27){
      int dz=key/9-1, dy=(key%9)/3-1, dxx=key%3-1;
      int z=d0+dz, y=h0+dy, x=w0+dxx;
      float l = LD(lbias, h*27+key);
      #pragma unroll
      for(int d=0;d<24;d++) l += qnr[d]*LD(ltok, (h*24+d)*27+key);
      lt[key]=l;
      if((unsigned)z<16u && (unsigned)y<40u && (unsigned)x<40u){
        int nb = n + dz*1600 + dy*40 + dxx;
        const float* kr = K + (h*NN+nb)*24;
        a = LD(rbl, h*27+key);
        #pragma unroll
        for(int d=0;d<24;d++) a += qsr[d]*kr[d];
      } else a = NEGINF;
    } else {
      int p = key-27;
      const float* kr = KPN + (h*50+p)*24;
      a = TAB[rpi[n*50+p]*4 + h];
      #pragma unroll
      for(int d=0;d<24;d++) a += qsr[d]*kr[d];
    }
    av[key]=a;
  }
  __syncthreads();
  float m = NEGINF;
  for(int i=0;i<77;i++) m = fmaxf(m, av[i]);
  for(int key=t; key<77; key+=64) pv[key] = __expf(av[key]-m);
  __syncthreads();
  float s=0.f;
  for(int i=0;i<77;i++) s += pv[i];
  float inv = 1.0f/s;
  if(t<24){
    float acc=0.f;
    for(int l=0;l<27;l++){
      int dz=l/9-1, dy=(l%9)/3-1, dxx=l%3-1;
      int z=d0+dz, y=h0+dy, x=w0+dxx;
      if((unsigned)z<16u && (unsigned)y<40u && (unsigned)x<40u){
        int nb = n + dz*1600 + dy*40 + dxx;
        acc += (pv[l]*inv + lt[l]) * VSA[(h*NN+nb)*24+t];
      }
    }
    for(int p=0;p<50;p++) acc += pv[27+p]*inv * VP[(h*50+p)*24+t];
    XSA[(h*24+t)*NN + n] = acc;
  }
}

// ---------------- K8a: cross-attn row norms over N for q and k ----------------
__global__ void k_canorm(const float* __restrict__ Q, const float* __restrict__ K,
                         float* __restrict__ RINV){
  __shared__ float red[4];
  int bb=blockIdx.x;
  int which=bb/96, cd=bb%96, h=cd/24, d=cd%24;
  const float* src = which? K : Q;
  float s=0.f;
  for(int n=threadIdx.x; n<NN; n+=256){ float v=src[(h*NN+n)*24+d]; s+=v*v; }
  #pragma unroll
  for(int off=32;off;off>>=1) s += __shfl_down(s, off);
  int lane=threadIdx.x&63, wid=threadIdx.x>>6;
  if(lane==0) red[wid]=s;
  __syncthreads();
  if(threadIdx.x==0){
    float tt = red[0]+red[1]+red[2]+red[3];
    RINV[bb] = 1.0f/fmaxf(sqrtf(tt),1e-12f);
  }
}

// ---------------- K8b: S[h][d][e] = sum_n q[h,n,d]*k[h,n,e] ----------------
__global__ void k_cascore(const float* __restrict__ Q, const float* __restrict__ K,
                          float* __restrict__ SCA){
  __shared__ float red[4*24];
  int bb=blockIdx.x, h=bb/24, d=bb%24;
  float acc[24];
  #pragma unroll
  for(int e=0;e<24;e++) acc[e]=0.f;
  for(int n=threadIdx.x; n<NN; n+=256){
    float qv = Q[(h*NN+n)*24+d];
    const float* kr = K + (h*NN+n)*24;
    #pragma unroll
    for(int e=0;e<24;e++) acc[e] += qv*kr[e];
  }
  int lane=threadIdx.x&63, wid=threadIdx.x>>6;
  #pragma unroll
  for(int e=0;e<24;e++){
    float v=acc[e];
    #pragma unroll
    for(int off=32;off;off>>=1) v += __shfl_down(v, off);
    if(lane==0) red[wid*24+e]=v;
  }
  __syncthreads();
  if(threadIdx.x<24){
    int e=threadIdx.x;
    SCA[(h*24+d)*24+e] = red[e]+red[24+e]+red[48+e]+red[72+e];
  }
}

// ---------------- K8c: a_ca = softmax(S*qinv*kinv*t2) over e ----------------
__global__ void k_casm(const float* __restrict__ SCA, const float* __restrict__ RINV,
                       const void* __restrict__ t2, float* __restrict__ ACA){
  int t=threadIdx.x;
  if(t>=96) return;
  int h=t/24, d=t%24;
  float tv = LD(t2,h);
  float qi = RINV[h*24+d];
  float v[24]; float m=NEGINF;
  #pragma unroll
  for(int e=0;e<24;e++){
    v[e] = SCA[(h*24+d)*24+e]*qi*RINV[96+h*24+e]*tv;
    m = fmaxf(m, v[e]);
  }
  float s=0.f;
  #pragma unroll
  for(int e=0;e<24;e++){ v[e]=__expf(v[e]-m); s+=v[e]; }
  float inv=1.0f/s;
  #pragma unroll
  for(int e=0;e<24;e++) ACA[(h*24+d)*24+e] = v[e]*inv;
}

// ---------------- K8d: x_ca[c][n] = sum_e A[h,d,e]*v_ca[h,n,e] ----------------
__global__ void k_caout(const float* __restrict__ ACA, const float* __restrict__ VCA,
                        float* __restrict__ XCA){
  int c = blockIdx.y, h=c/24, d=c%24;
  int n = blockIdx.x*64 + threadIdx.x;
  float ar[24];
  #pragma unroll
  for(int e=0;e<24;e++) ar[e] = ACA[(h*24+d)*24+e];
  const float* vr = VCA + (h*NN+n)*24;
  float a=0.f;
  #pragma unroll
  for(int e=0;e<24;e++) a += ar[e]*vr[e];
  XCA[c*NN+n] = a;
}

// ---------------- K9: epa proj + ax = xt + gamma*epa -> SKIP[c][n] ----------------
__global__ void k_epa(const float* __restrict__ XSA, const float* __restrict__ XCA,
                      const void* __restrict__ x, const void* __restrict__ gamma,
                      const void* __restrict__ o1w, const void* __restrict__ o1b,
                      const void* __restrict__ o2w, const void* __restrict__ o2b,
                      float* __restrict__ SKIP){
  int n = blockIdx.x*256 + threadIdx.x;
  int c0 = blockIdx.y*16;
  bool first = (c0 < 48);
  const float* src = first? XSA : XCA;
  const float* wp = (const float*)(first? o1w : o2w);
  const void* bb = first? o1b : o2b;
  int cb = first? c0 : c0-48;
  float acc[16];
  #pragma unroll
  for(int j=0;j<16;j++) acc[j]=0.f;
  for(int c=0;c<96;c+=4){
    float v0=src[(c+0)*NN+n], v1=src[(c+1)*NN+n], v2=src[(c+2)*NN+n], v3=src[(c+3)*NN+n];
    #pragma unroll
    for(int j=0;j<16;j++){
      const float4 wv = *reinterpret_cast<const float4*>(wp + (cb+j)*96 + c);
      acc[j] += wv.x*v0 + wv.y*v1 + wv.z*v2 + wv.w*v3;
    }
  }
  #pragma unroll
  for(int j=0;j<16;j++){
    int c = c0+j;
    float e = acc[j] + LD(bb, cb+j);
    SKIP[c*NN+n] = LD(x, c*NN+n) + 1.0f + LD(gamma,c)*e;
  }
}

// ---------------- conv weight repack, layout WF[t][tap][o][i] ----------------
__global__ void k_wconv(const void* w0, const void* w1, const void* w2, const void* w3,
                        float* __restrict__ WF){
  int e = blockIdx.x*256 + threadIdx.x;
  if(e >= 4*WSZ) return;
  int t = e/WSZ, r = e%WSZ;
  int tap = r/9216, r2 = r%9216, o = r2/96, i = r2%96;
  const void* w = (t==0)? w0 : (t==1)? w1 : (t==2)? w2 : w3;
  WF[e] = LD(w, (o*96+i)*27 + tap);
}

// ---------------- K10: conv3x3x3 + BN + optional residual + lrelu ----------------
__global__ void k_conv(const float* __restrict__ in, const float* __restrict__ WF,
                       const void* __restrict__ bnp, const float* __restrict__ res,
                       float* __restrict__ out){
  int n = blockIdx.x*256 + threadIdx.x;
  int o0 = blockIdx.y*16;
  int X=n/640, rr=n%640, Y=rr/16, Z=rr%16;   // resblock grid (Hh,Ww,Dd)
  float acc[16];
  #pragma unroll
  for(int j=0;j<16;j++) acc[j]=0.f;
  for(int tap=0;tap<27;tap++){
    int dx=tap/9-1, dy=(tap%9)/3-1, dz=tap%3-1;
    int X1=X+dx, Y1=Y+dy, Z1=Z+dz;
    bool ok = (unsigned)X1<40u && (unsigned)Y1<40u && (unsigned)Z1<16u;
    int nb = n + dx*640 + dy*16 + dz;
    const float* wbase = WF + tap*9216 + o0*96;  // + j*96 + i  (uniform -> s_load)
    for(int i=0;i<96;i+=4){
      float v0 = ok? in[(i+0)*NN+nb] : 0.f;
      float v1 = ok? in[(i+1)*NN+nb] : 0.f;
      float v2 = ok? in[(i+2)*NN+nb] : 0.f;
      float v3 = ok? in[(i+3)*NN+nb] : 0.f;
      #pragma unroll
      for(int j=0;j<16;j++){
        const float4 wv = *reinterpret_cast<const float4*>(wbase + j*96 + i);
        acc[j] += wv.x*v0 + wv.y*v1 + wv.z*v2 + wv.w*v3;
      }
    }
  }
  #pragma unroll
  for(int j=0;j<16;j++){
    int o = o0+j;
    float g=LD(bnp,o), b=LD(bnp,96+o), mu=LD(bnp,192+o), var=LD(bnp,288+o);
    float y = (acc[j]-mu)*rsqrtf(var+1e-5f)*g + b;
    if(res) y += res[o*NN+n];
    out[o*NN+n] = (y>=0.f)? y : 0.01f*y;
  }
}

// ---------------- K11: out = skip + conv8(r2) + b8 ----------------
__global__ void k_final(const float* __restrict__ SKIP, const float* __restrict__ R,
                        const void* __restrict__ w, const void* __restrict__ b,
                        float* __restrict__ out){
  int n = blockIdx.x*256 + threadIdx.x;
  int c0 = blockIdx.y*16;
  const float* wp = (const float*)w;
  float acc[16];
  #pragma unroll
  for(int j=0;j<16;j++) acc[j]=0.f;
  for(int i=0;i<96;i+=4){
    float v0=R[(i+0)*NN+n], v1=R[(i+1)*NN+n], v2=R[(i+2)*NN+n], v3=R[(i+3)*NN+n];
    #pragma unroll
    for(int j=0;j<16;j++){
      const float4 wv = *reinterpret_cast<const float4*>(wp + (c0+j)*96 + i);
      acc[j] += wv.x*v0 + wv.y*v1 + wv.z*v2 + wv.w*v3;
    }
  }
  #pragma unroll
  for(int j=0;j<16;j++){
    int c = c0+j;
    out[c*NN+n] = SKIP[c*NN+n] + acc[j] + LD(b,c);
  }
}

extern "C" void kernel_launch(void* const* d_in, const int* in_sizes, int n_in,
                              void* d_out, int out_size, void* d_ws, size_t ws_size,
                              hipStream_t stream){
  const void* x     = d_in[0];
  const int*  rpi   = (const int*)d_in[1];
  const void* rct   = d_in[2];
  const void* sls   = d_in[3];
  const void* nw    = d_in[4];
  const void* nb    = d_in[5];
  const void* gamma = d_in[6];
  const void* wqkvv = d_in[7];
  const void* temp  = d_in[8];
  const void* temp2 = d_in[9];
  const void* qe    = d_in[10];
  const void* rbl   = d_in[11];
  const void* ltok  = d_in[12];
  const void* lbias = d_in[13];
  const void* srw   = d_in[14];
  const void* srb   = d_in[15];
  const void* epaw  = d_in[16];
  const void* epab  = d_in[17];
  const void* wkv   = d_in[18];
  const void* c1w   = d_in[19];
  const void* c1b   = d_in[20];
  const void* c2w   = d_in[21];
  const void* c2b   = d_in[22];
  const void* o1w   = d_in[23];
  const void* o1b   = d_in[24];
  const void* o2w   = d_in[25];
  const void* o2b   = d_in[26];
  const void* w51a  = d_in[27];
  const void* bn51a = d_in[28];
  const void* w51b  = d_in[29];
  const void* bn51b = d_in[30];
  const void* w52a  = d_in[31];
  const void* bn52a = d_in[32];
  const void* w52b  = d_in[33];
  const void* bn52b = d_in[34];
  const void* w8    = d_in[35];
  const void* b8    = d_in[36];

  float* ws = (float*)d_ws;
  const size_t S = SSLOT;
  // slot layout with reuse (lifetimes verified against launch order)
  float* XN  = ws;          // dead after k_sr -> reused as SKIP
  float* Q   = ws + 1*S;    // dead after k_cascore -> reused as T1
  float* Kb  = ws + 2*S;    // dead after k_cascore -> reused as T2
  float* VCA = ws + 3*S;    // dead after k_caout
  float* VSA = ws + 4*S;    // dead after k_attn  -> reused as T3
  float* QN  = ws + 5*S;
  float* QS  = ws + 6*S;
  float* XP2 = ws + 7*S;    // dead after k_pool  -> reused as XSA
  float* XSA = ws + 7*S;
  float* XCA = ws + 8*S;
  float* SKIP= XN;
  float* T1  = Q;
  float* T2  = Kb;
  float* T3  = VSA;
  float* SM  = ws + 9*S;
  float* pooled = SM;          // 4800
  float* KP     = SM + 4800;   // 4800
  float* VP     = SM + 9600;   // 4800
  float* KPN    = SM + 14400;  // 4800
  float* TAB    = SM + 19200;  // 16384
  float* RINV   = SM + 35584;  // 192
  float* SCA    = SM + 35776;  // 2304
  float* ACA    = SM + 38080;  // 2304
  float* WF     = SM + 40960;  // 4*248832 f32 repacked conv weights

  k_wconv <<<3888,  256, 0, stream>>>(w51a, w51b, w52a, w52b, WF);
  k_ln    <<<100,   256, 0, stream>>>(x, nw, nb, XN);
  k_qkvv  <<<dim3(100,24), 256, 0, stream>>>(XN, wqkvv, Q);
  k_qs    <<<400,   256, 0, stream>>>(Q, temp, sls, qe, QN, QS);
  k_sr    <<<dim3(100,6),  256, 0, stream>>>(XN, srw, srb, XP2);
  k_pool  <<<4800,  64,  0, stream>>>(XP2, pooled);
  k_lnkv  <<<50,    256, 0, stream>>>(pooled, epaw, epab, wkv, KP, VP);
  k_kpn   <<<1,     256, 0, stream>>>(KP, KPN);
  k_tab   <<<4096,  512, 0, stream>>>(rct, c1w, c1b, c2w, c2b, TAB);
  k_attn  <<<NHh*NN, 64, 0, stream>>>(QS, QN, Kb, VSA, KPN, VP, TAB, rpi,
                                      rbl, ltok, lbias, XSA);
  k_canorm<<<192,   256, 0, stream>>>(Q, Kb, RINV);
  k_cascore<<<96,   256, 0, stream>>>(Q, Kb, SCA);
  k_casm  <<<1,     128, 0, stream>>>(SCA, RINV, temp2, ACA);
  k_caout <<<dim3(400,96), 64, 0, stream>>>(ACA, VCA, XCA);
  k_epa   <<<dim3(100,6),  256, 0, stream>>>(XSA, XCA, x, gamma, o1w, o1b, o2w, o2b, SKIP);
  // resblock 1
  k_conv  <<<dim3(100,6),  256, 0, stream>>>(SKIP, WF,          bn51a, nullptr, T1);
  k_conv  <<<dim3(100,6),  256, 0, stream>>>(T1,   WF+WSZ,      bn51b, SKIP,    T2);
  // resblock 2
  k_conv  <<<dim3(100,6),  256, 0, stream>>>(T2,   WF+2*WSZ,    bn52a, nullptr, T1);
  k_conv  <<<dim3(100,6),  256, 0, stream>>>(T1,   WF+3*WSZ,    bn52b, T2,      T3);
  k_final <<<dim3(100,6),  256, 0, stream>>>(SKIP, T3, w8, b8, (float*)d_out);
}

// Round 3
// 940.767 us; speedup vs baseline: 2.3905x; 2.3905x over previous
//
#include <hip/hip_runtime.h>
#include <hip/hip_bf16.h>

// Problem constants
#define NN 25600      // D*H*W = 16*40*40 ; conv grid n = X*640+Y*16+Z, (X,Y,Z)=(40,40,16)
#define CC 96
#define NHh 4
#define HDd 24
#define SSLOT 2457600 // NN*CC floats per workspace slot
#define WSZ 248832    // 27*96*96 elems per conv weight tensor

typedef unsigned short ushort_t;
typedef float f32x4 __attribute__((ext_vector_type(4)));
typedef short s16x8 __attribute__((ext_vector_type(8)));

// All tensors are float32 on device (per reference dtypes).
__device__ __forceinline__ float LD(const void* p, int i){
  return ((const float*)p)[i];
}
__device__ __forceinline__ float b2f(ushort_t u){ return __uint_as_float(((unsigned)u)<<16); }
__device__ __forceinline__ ushort_t f2b(float f){   // RNE bf16 round
  unsigned u = __float_as_uint(f);
  unsigned r = (u + 0x7fffu + ((u>>16)&1u))>>16;
  return (ushort_t)r;
}

#define NEGINF (-3.0e38f)

// ---------------- K1: xt = x+1, LayerNorm over C, store XN[c][n] ----------------
__global__ void k_ln(const void* __restrict__ x, const void* __restrict__ nw,
                     const void* __restrict__ nb, float* __restrict__ XN){
  int n = blockIdx.x*256 + threadIdx.x;
  float s=0.f, ss=0.f;
  for(int c=0;c<CC;c++){ float v = LD(x, c*NN+n)+1.0f; s+=v; ss+=v*v; }
  float mu = s*(1.0f/CC);
  float var = ss*(1.0f/CC) - mu*mu;
  float inv = rsqrtf(var + 1e-5f);
  for(int c=0;c<CC;c++){
    float v = LD(x, c*NN+n)+1.0f;
    XN[c*NN+n] = (v-mu)*inv*LD(nw,c) + LD(nb,c);
  }
}

// ---------------- K2: qkvv = xn @ w_qkvv^T -> Q/K/VCA/VSA [h][n][d] ----------------
__global__ void k_qkvv(const float* __restrict__ XN, const void* __restrict__ w,
                       float* __restrict__ out){ // out = base of Q; slots s*SSLOT
  int n = blockIdx.x*256 + threadIdx.x;
  int o0 = blockIdx.y*16;
  const float* wp = (const float*)w;
  float acc[16];
  #pragma unroll
  for(int j=0;j<16;j++) acc[j]=0.f;
  for(int c=0;c<96;c+=4){
    float v0=XN[(c+0)*NN+n], v1=XN[(c+1)*NN+n], v2=XN[(c+2)*NN+n], v3=XN[(c+3)*NN+n];
    #pragma unroll
    for(int j=0;j<16;j++){
      const float4 wv = *reinterpret_cast<const float4*>(wp + (o0+j)*96 + c);
      acc[j] += wv.x*v0 + wv.y*v1 + wv.z*v2 + wv.w*v3;
    }
  }
  #pragma unroll
  for(int j=0;j<16;j++){
    int jj=o0+j, s=jj/96, rr=jj%96, h=rr/24, dd=rr%24;
    out[s*SSLOT + (h*NN+n)*24 + dd] = acc[j];
  }
}

// ---------------- K3: qn = l2(q), qs = (qn+qe)*softplus(T)*sls ----------------
__global__ void k_qs(const float* __restrict__ Q, const void* __restrict__ temp,
                     const void* __restrict__ sls, const void* __restrict__ qe,
                     float* __restrict__ QN, float* __restrict__ QS){
  int id = blockIdx.x*256 + threadIdx.x;
  if(id >= NHh*NN) return;
  int h = id/NN, n = id%NN;
  const float* qr = Q + (h*NN+n)*24;
  float qv[24]; float ss=0.f;
  #pragma unroll
  for(int d=0;d<24;d++){ qv[d]=qr[d]; ss+=qv[d]*qv[d]; }
  float inv = 1.0f/fmaxf(sqrtf(ss), 1e-12f);
  float t = LD(temp,h);
  float sp = log1pf(expf(t)) * LD(sls,0);
  #pragma unroll
  for(int d=0;d<24;d++){
    float qn = qv[d]*inv;
    QN[(h*NN+n)*24+d] = qn;
    QS[(h*NN+n)*24+d] = (qn + LD(qe, h*24+d))*sp;
  }
}

// ---------------- K4: xp2 = gelu(sr_w @ xn + sr_b), [c][n] ----------------
__global__ void k_sr(const float* __restrict__ XN, const void* __restrict__ w,
                     const void* __restrict__ b, float* __restrict__ XP2){
  int n = blockIdx.x*256 + threadIdx.x;
  int o0 = blockIdx.y*16;
  const float* wp = (const float*)w;
  float acc[16];
  #pragma unroll
  for(int j=0;j<16;j++) acc[j]=0.f;
  for(int c=0;c<96;c+=4){
    float v0=XN[(c+0)*NN+n], v1=XN[(c+1)*NN+n], v2=XN[(c+2)*NN+n], v3=XN[(c+3)*NN+n];
    #pragma unroll
    for(int j=0;j<16;j++){
      const float4 wv = *reinterpret_cast<const float4*>(wp + (o0+j)*96 + c);
      acc[j] += wv.x*v0 + wv.y*v1 + wv.z*v2 + wv.w*v3;
    }
  }
  #pragma unroll
  for(int j=0;j<16;j++){
    float y = acc[j] + LD(b, o0+j);
    y = 0.5f*y*(1.0f + erff(y*0.70710678118f));  // exact gelu
    XP2[(o0+j)*NN+n] = y;
  }
}

// ---------------- K5: 8x8x8 average pool over (X,Y,Z)=(40,40,16) view ----------------
__global__ void k_pool(const float* __restrict__ XP2, float* __restrict__ pooled){
  int bb = blockIdx.x;
  int c = bb % CC, p = bb / CC;
  int ph = p/10, pw = (p%10)/2, pd = p%2;
  float s = 0.f;
  for(int t=threadIdx.x; t<512; t+=64){
    int i=t>>6, j=(t>>3)&7, k=t&7;
    int m = (ph*8+i)*640 + (pw*8+j)*16 + (pd*8+k);
    s += XP2[c*NN+m];
  }
  #pragma unroll
  for(int off=32;off;off>>=1) s += __shfl_down(s, off);
  if(threadIdx.x==0) pooled[p*CC+c] = s*(1.0f/512.0f);
}

// ---------------- K5b: LN(pooled) then kv = xp @ w_kv^T -> KP/VP [h][p][d] ----------------
__global__ void k_lnkv(const float* __restrict__ pooled, const void* __restrict__ ew,
                       const void* __restrict__ eb, const void* __restrict__ wkv,
                       float* __restrict__ KP, float* __restrict__ VP){
  __shared__ float row[96], lnr[96], st[2];
  int p = blockIdx.x, t = threadIdx.x;
  if(t<96) row[t] = pooled[p*96+t];
  __syncthreads();
  if(t==0){
    float s=0.f, ss=0.f;
    for(int c=0;c<96;c++){ float v=row[c]; s+=v; ss+=v*v; }
    float mu=s*(1.0f/96.0f);
    float var=ss*(1.0f/96.0f)-mu*mu;
    st[0]=mu; st[1]=rsqrtf(var+1e-5f);
  }
  __syncthreads();
  if(t<96) lnr[t] = (row[t]-st[0])*st[1]*LD(ew,t) + LD(eb,t);
  __syncthreads();
  if(t<192){
    float a=0.f;
    for(int c=0;c<96;c++) a += LD(wkv, t*96+c)*lnr[c];
    int g=t/24, d=t%24;
    if(g<4) KP[(g*50+p)*24+d]=a;
    else    VP[((g-4)*50+p)*24+d]=a;
  }
}

// ---------------- K5c: k_pool l2-normalize over d ----------------
__global__ void k_kpn(const float* __restrict__ KP, float* __restrict__ KPN){
  int t = threadIdx.x;
  if(t>=200) return;
  const float* r = KP + t*24;
  float ss=0.f;
  #pragma unroll
  for(int d=0;d<24;d++) ss += r[d]*r[d];
  float inv = 1.0f/fmaxf(sqrtf(ss),1e-12f);
  #pragma unroll
  for(int d=0;d<24;d++) KPN[t*24+d] = r[d]*inv;
}

// ---------------- K6: cpb MLP -> tab[T][NH] ----------------
__global__ void k_tab(const void* __restrict__ rct, const void* __restrict__ w1,
                      const void* __restrict__ b1, const void* __restrict__ w2,
                      const void* __restrict__ b2, float* __restrict__ TAB){
  __shared__ float red[32];
  int tt = blockIdx.x, j = threadIdx.x;
  float r0=LD(rct,tt*3), r1=LD(rct,tt*3+1), r2=LD(rct,tt*3+2);
  float hj = r0*LD(w1,j*3) + r1*LD(w1,j*3+1) + r2*LD(w1,j*3+2) + LD(b1,j);
  hj = fmaxf(hj, 0.f);
  int lane=j&63, wid=j>>6;
  for(int h=0;h<4;h++){
    float v = hj*LD(w2, h*512+j);
    #pragma unroll
    for(int off=32;off;off>>=1) v += __shfl_down(v, off);
    if(lane==0) red[wid*4+h]=v;
  }
  __syncthreads();
  if(j<4){
    float s=0.f;
    for(int w=0;w<8;w++) s += red[w*4+j];
    TAB[tt*4+j] = s + LD(b2,j);
  }
}

// ---------------- K7: fused local+pool attention per (h,n), one wave/block ----------------
__global__ void k_attn(const float* __restrict__ QS, const float* __restrict__ QN,
                       const float* __restrict__ K,  const float* __restrict__ VSA,
                       const float* __restrict__ KPN,const float* __restrict__ VP,
                       const float* __restrict__ TAB,const int* __restrict__ rpi,
                       const void* __restrict__ rbl, const void* __restrict__ ltok,
                       const void* __restrict__ lbias, float* __restrict__ XSA){
  __shared__ float qsr[24], qnr[24], av[80], pv[80], lt[28];
  int bb = blockIdx.x;
  int h = bb % NHh, n = bb / NHh;
  int t = threadIdx.x;
  if(t<24){ qsr[t]=QS[(h*NN+n)*24+t]; qnr[t]=QN[(h*NN+n)*24+t]; }
  __syncthreads();
  int d0=n/1600, rr=n%1600, h0=rr/40, w0=rr%40;  // original (D,H,W) grid
  for(int key=t; key<77; key+=64){
    float a;
    if(key<27){
      int dz=key/9-1, dy=(key%9)/3-1, dxx=key%3-1;
      int z=d0+dz, y=h0+dy, x=w0+dxx;
      float l = LD(lbias, h*27+key);
      #pragma unroll
      for(int d=0;d<24;d++) l += qnr[d]*LD(ltok, (h*24+d)*27+key);
      lt[key]=l;
      if((unsigned)z<16u && (unsigned)y<40u && (unsigned)x<40u){
        int nb = n + dz*1600 + dy*40 + dxx;
        const float* kr = K + (h*NN+nb)*24;
        a = LD(rbl, h*27+key);
        #pragma unroll
        for(int d=0;d<24;d++) a += qsr[d]*kr[d];
      } else a = NEGINF;
    } else {
      int p = key-27;
      const float* kr = KPN + (h*50+p)*24;
      a = TAB[rpi[n*50+p]*4 + h];
      #pragma unroll
      for(int d=0;d<24;d++) a += qsr[d]*kr[d];
    }
    av[key]=a;
  }
  __syncthreads();
  float m = NEGINF;
  for(int i=0;i<77;i++) m = fmaxf(m, av[i]);
  for(int key=t; key<77; key+=64) pv[key] = __expf(av[key]-m);
  __syncthreads();
  float s=0.f;
  for(int i=0;i<77;i++) s += pv[i];
  float inv = 1.0f/s;
  if(t<24){
    float acc=0.f;
    for(int l=0;l<27;l++){
      int dz=l/9-1, dy=(l%9)/3-1, dxx=l%3-1;
      int z=d0+dz, y=h0+dy, x=w0+dxx;
      if((unsigned)z<16u && (unsigned)y<40u && (unsigned)x<40u){
        int nb = n + dz*1600 + dy*40 + dxx;
        acc += (pv[l]*inv + lt[l]) * VSA[(h*NN+nb)*24+t];
      }
    }
    for(int p=0;p<50;p++) acc += pv[27+p]*inv * VP[(h*50+p)*24+t];
    XSA[(h*24+t)*NN + n] = acc;
  }
}

// ---------------- K8a: cross-attn row norms over N for q and k ----------------
__global__ void k_canorm(const float* __restrict__ Q, const float* __restrict__ K,
                         float* __restrict__ RINV){
  __shared__ float red[4];
  int bb=blockIdx.x;
  int which=bb/96, cd=bb%96, h=cd/24, d=cd%24;
  const float* src = which? K : Q;
  float s=0.f;
  for(int n=threadIdx.x; n<NN; n+=256){ float v=src[(h*NN+n)*24+d]; s+=v*v; }
  #pragma unroll
  for(int off=32;off;off>>=1) s += __shfl_down(s, off);
  int lane=threadIdx.x&63, wid=threadIdx.x>>6;
  if(lane==0) red[wid]=s;
  __syncthreads();
  if(threadIdx.x==0){
    float tt = red[0]+red[1]+red[2]+red[3];
    RINV[bb] = 1.0f/fmaxf(sqrtf(tt),1e-12f);
  }
}

// ---------------- K8b: S[h][d][e] = sum_n q[h,n,d]*k[h,n,e] ----------------
__global__ void k_cascore(const float* __restrict__ Q, const float* __restrict__ K,
                          float* __restrict__ SCA){
  __shared__ float red[4*24];
  int bb=blockIdx.x, h=bb/24, d=bb%24;
  float acc[24];
  #pragma unroll
  for(int e=0;e<24;e++) acc[e]=0.f;
  for(int n=threadIdx.x; n<NN; n+=256){
    float qv = Q[(h*NN+n)*24+d];
    const float* kr = K + (h*NN+n)*24;
    #pragma unroll
    for(int e=0;e<24;e++) acc[e] += qv*kr[e];
  }
  int lane=threadIdx.x&63, wid=threadIdx.x>>6;
  #pragma unroll
  for(int e=0;e<24;e++){
    float v=acc[e];
    #pragma unroll
    for(int off=32;off;off>>=1) v += __shfl_down(v, off);
    if(lane==0) red[wid*24+e]=v;
  }
  __syncthreads();
  if(threadIdx.x<24){
    int e=threadIdx.x;
    SCA[(h*24+d)*24+e] = red[e]+red[24+e]+red[48+e]+red[72+e];
  }
}

// ---------------- K8c: a_ca = softmax(S*qinv*kinv*t2) over e ----------------
__global__ void k_casm(const float* __restrict__ SCA, const float* __restrict__ RINV,
                       const void* __restrict__ t2, float* __restrict__ ACA){
  int t=threadIdx.x;
  if(t>=96) return;
  int h=t/24, d=t%24;
  float tv = LD(t2,h);
  float qi = RINV[h*24+d];
  float v[24]; float m=NEGINF;
  #pragma unroll
  for(int e=0;e<24;e++){
    v[e] = SCA[(h*24+d)*24+e]*qi*RINV[96+h*24+e]*tv;
    m = fmaxf(m, v[e]);
  }
  float s=0.f;
  #pragma unroll
  for(int e=0;e<24;e++){ v[e]=__expf(v[e]-m); s+=v[e]; }
  float inv=1.0f/s;
  #pragma unroll
  for(int e=0;e<24;e++) ACA[(h*24+d)*24+e] = v[e]*inv;
}

// ---------------- K8d: x_ca[c][n] = sum_e A[h,d,e]*v_ca[h,n,e] ----------------
__global__ void k_caout(const float* __restrict__ ACA, const float* __restrict__ VCA,
                        float* __restrict__ XCA){
  int c = blockIdx.y, h=c/24, d=c%24;
  int n = blockIdx.x*64 + threadIdx.x;
  float ar[24];
  #pragma unroll
  for(int e=0;e<24;e++) ar[e] = ACA[(h*24+d)*24+e];
  const float* vr = VCA + (h*NN+n)*24;
  float a=0.f;
  #pragma unroll
  for(int e=0;e<24;e++) a += ar[e]*vr[e];
  XCA[c*NN+n] = a;
}

// ---------------- K9: epa proj + ax = xt + gamma*epa -> SKIPF f32[n][96] + SKIPH bf16[n][96] ----------------
__global__ void k_epa(const float* __restrict__ XSA, const float* __restrict__ XCA,
                      const void* __restrict__ x, const void* __restrict__ gamma,
                      const void* __restrict__ o1w, const void* __restrict__ o1b,
                      const void* __restrict__ o2w, const void* __restrict__ o2b,
                      float* __restrict__ SKIPF, ushort_t* __restrict__ SKIPH){
  int n = blockIdx.x*256 + threadIdx.x;
  int c0 = blockIdx.y*16;
  bool first = (c0 < 48);
  const float* src = first? XSA : XCA;
  const float* wp = (const float*)(first? o1w : o2w);
  const void* bb = first? o1b : o2b;
  int cb = first? c0 : c0-48;
  float acc[16];
  #pragma unroll
  for(int j=0;j<16;j++) acc[j]=0.f;
  for(int c=0;c<96;c+=4){
    float v0=src[(c+0)*NN+n], v1=src[(c+1)*NN+n], v2=src[(c+2)*NN+n], v3=src[(c+3)*NN+n];
    #pragma unroll
    for(int j=0;j<16;j++){
      const float4 wv = *reinterpret_cast<const float4*>(wp + (cb+j)*96 + c);
      acc[j] += wv.x*v0 + wv.y*v1 + wv.z*v2 + wv.w*v3;
    }
  }
  #pragma unroll
  for(int j=0;j<16;j++){
    int c = c0+j;
    float e = acc[j] + LD(bb, cb+j);
    float v = LD(x, c*NN+n) + 1.0f + LD(gamma,c)*e;
    SKIPF[n*96+c] = v;
    SKIPH[n*96+c] = f2b(v);
  }
}

// ---------------- prep: conv weights -> bf16 WB[t][tap][o][i] ----------------
__global__ void k_prep(const void* w0, const void* w1, const void* w2, const void* w3,
                       ushort_t* __restrict__ WB){
  int e = blockIdx.x*256 + threadIdx.x;
  if(e >= 4*WSZ) return;
  int t = e/WSZ, r = e%WSZ;
  int tap = r/9216, r2 = r%9216, o = r2/96, i = r2%96;
  const void* w = (t==0)? w0 : (t==1)? w1 : (t==2)? w2 : w3;
  WB[e] = f2b(LD(w, (o*96+i)*27 + tap));
}

// ---------------- prep: BN scale/shift per conv: BNS[t*192 + {o, 96+o}] ----------------
__global__ void k_bnprep(const void* b0, const void* b1, const void* b2, const void* b3,
                         float* __restrict__ BNS){
  int id = threadIdx.x;
  if(id >= 384) return;
  int t = id/96, o = id%96;
  const void* bn = (t==0)? b0 : (t==1)? b1 : (t==2)? b2 : b3;
  float g=LD(bn,o), b=LD(bn,96+o), mu=LD(bn,192+o), var=LD(bn,288+o);
  float s = g*rsqrtf(var+1e-5f);
  BNS[t*192+o] = s;
  BNS[t*192+96+o] = b - mu*s;
}

// ---------------- K10: MFMA implicit-GEMM conv3x3x3 + BN + res + lrelu ----------------
// Block: 64 n x 96 o, 4 waves split the 27 taps (K-split), LDS reduce.
__global__ __launch_bounds__(256,2) void k_convm(
    const ushort_t* __restrict__ IN,   // bf16 [n][96]
    const ushort_t* __restrict__ WB,   // bf16 [27][96][96] (o-major, i contiguous)
    const float* __restrict__ BNS,     // [192] scale|shift
    const float* __restrict__ resf,    // f32 [n][96] or null
    ushort_t* __restrict__ outh,       // bf16 [n][96]
    float* __restrict__ outf)          // f32 [n][96] or null
{
  __shared__ float red[4][48][68];   // 52.2 KB -> 2 blocks/CU
  int tid = threadIdx.x;
  int w = tid>>6, lane = tid&63;
  int lan = lane&15, grp = lane>>4;
  int n0 = blockIdx.x*64;

  int nj[4], Xj[4], Yj[4], Zj[4];
  #pragma unroll
  for(int j=0;j<4;j++){
    int n = n0 + j*16 + lan;
    nj[j]=n; Xj[j]=n/640; int rr=n%640; Yj[j]=rr/16; Zj[j]=rr&15;
  }

  f32x4 acc[6][4];
  #pragma unroll
  for(int mt=0;mt<6;mt++)
    #pragma unroll
    for(int j=0;j<4;j++) acc[mt][j] = (f32x4)(0.f);

  int lo = (w*27)>>2, hi = ((w+1)*27)>>2;   // 6,7,7,7 taps
  for(int tap=lo; tap<hi; ++tap){
    int dx=tap/9-1, dy=(tap%9)/3-1, dz=tap%3-1;
    int off = dx*640 + dy*16 + dz;
    const ushort_t* wt = WB + tap*9216;
    const ushort_t* sp[4]; bool ok[4];
    #pragma unroll
    for(int j=0;j<4;j++){
      ok[j] = (unsigned)(Xj[j]+dx)<40u && (unsigned)(Yj[j]+dy)<40u && (unsigned)(Zj[j]+dz)<16u;
      sp[j] = IN + (nj[j]+off)*96 + grp*8;
    }
    #pragma unroll
    for(int s=0;s<3;s++){
      s16x8 a[6];
      #pragma unroll
      for(int mt=0;mt<6;mt++)
        a[mt] = *reinterpret_cast<const s16x8*>(wt + (mt*16+lan)*96 + s*32 + grp*8);
      #pragma unroll
      for(int j=0;j<4;j++){
        s16x8 b = {};
        if(ok[j]) b = *reinterpret_cast<const s16x8*>(sp[j] + s*32);
        #pragma unroll
        for(int mt=0;mt<6;mt++)
          acc[mt][j] = __builtin_amdgcn_mfma_f32_16x16x32_bf16(a[mt], b, acc[mt][j], 0,0,0);
      }
    }
  }

  // cross-wave reduce (2 chunks of 48 o) + fused epilogue
  int n_loc = tid&63;
  int ob = (tid>>6)*12;
  int n = n0 + n_loc;
  #pragma unroll
  for(int chunk=0; chunk<2; ++chunk){
    if(chunk) __syncthreads();
    #pragma unroll
    for(int m=0;m<3;m++){
      int mt = chunk*3+m;
      #pragma unroll
      for(int j=0;j<4;j++)
        #pragma unroll
        for(int r=0;r<4;r++)
          red[w][m*16 + grp*4 + r][j*16 + lan] = acc[mt][j][r];
    }
    __syncthreads();
    #pragma unroll
    for(int q=0;q<12;q++){
      int o = ob+q;
      float v = red[0][o][n_loc]+red[1][o][n_loc]+red[2][o][n_loc]+red[3][o][n_loc];
      int og = chunk*48 + o;
      v = v*BNS[og] + BNS[96+og];
      if(resf) v += resf[n*96+og];
      v = (v>=0.f)? v : 0.01f*v;
      if(outf) outf[n*96+og] = v;
      outh[n*96+og] = f2b(v);
    }
  }
}

// ---------------- K11: out[c][n] = skipf[n][c] + conv8(T3h)[c][n] + b8[c] ----------------
__global__ void k_final(const float* __restrict__ SKIPF, const ushort_t* __restrict__ T3H,
                        const void* __restrict__ w, const void* __restrict__ b,
                        float* __restrict__ out){
  int n = blockIdx.x*256 + threadIdx.x;
  const float* wp = (const float*)w;
  float h[96];
  #pragma unroll
  for(int i=0;i<96;i++) h[i] = b2f(T3H[n*96+i]);
  for(int c=0;c<96;c++){
    float a = LD(b,c);
    #pragma unroll
    for(int i=0;i<96;i+=4){
      a += wp[c*96+i+0]*h[i+0] + wp[c*96+i+1]*h[i+1]
         + wp[c*96+i+2]*h[i+2] + wp[c*96+i+3]*h[i+3];
    }
    out[c*NN+n] = SKIPF[n*96+c] + a;
  }
}

extern "C" void kernel_launch(void* const* d_in, const int* in_sizes, int n_in,
                              void* d_out, int out_size, void* d_ws, size_t ws_size,
                              hipStream_t stream){
  const void* x     = d_in[0];
  const int*  rpi   = (const int*)d_in[1];
  const void* rct   = d_in[2];
  const void* sls   = d_in[3];
  const void* nw    = d_in[4];
  const void* nb    = d_in[5];
  const void* gamma = d_in[6];
  const void* wqkvv = d_in[7];
  const void* temp  = d_in[8];
  const void* temp2 = d_in[9];
  const void* qe    = d_in[10];
  const void* rbl   = d_in[11];
  const void* ltok  = d_in[12];
  const void* lbias = d_in[13];
  const void* srw   = d_in[14];
  const void* srb   = d_in[15];
  const void* epaw  = d_in[16];
  const void* epab  = d_in[17];
  const void* wkv   = d_in[18];
  const void* c1w   = d_in[19];
  const void* c1b   = d_in[20];
  const void* c2w   = d_in[21];
  const void* c2b   = d_in[22];
  const void* o1w   = d_in[23];
  const void* o1b   = d_in[24];
  const void* o2w   = d_in[25];
  const void* o2b   = d_in[26];
  const void* w51a  = d_in[27];
  const void* bn51a = d_in[28];
  const void* w51b  = d_in[29];
  const void* bn51b = d_in[30];
  const void* w52a  = d_in[31];
  const void* bn52a = d_in[32];
  const void* w52b  = d_in[33];
  const void* bn52b = d_in[34];
  const void* w8    = d_in[35];
  const void* b8    = d_in[36];

  float* ws = (float*)d_ws;
  const size_t S = SSLOT;
  // f32 slots (lifetimes verified against launch order)
  float* XN    = ws;          // dead after k_sr -> SKIPF (n-major f32)
  float* SKIPF = ws;
  float* Q     = ws + 1*S;    // dead after k_cascore
  float* Kb    = ws + 2*S;    // dead after k_cascore -> T2F
  float* T2F   = ws + 2*S;
  float* VCA   = ws + 3*S;    // dead after k_caout
  float* VSA   = ws + 4*S;    // dead after k_attn -> SKIPH/T1H (bf16)
  float* QN    = ws + 5*S;    // dead after k_attn -> T2H/T3H (bf16)
  float* QS    = ws + 6*S;    // dead after k_attn
  float* XP2   = ws + 7*S;    // dead after k_pool -> XSA
  float* XSA   = ws + 7*S;
  float* XCA   = ws + 8*S;
  ushort_t* SKIPH = (ushort_t*)(ws + 4*S);
  ushort_t* T1H   = SKIPH + SSLOT;          // second half of slot 4
  ushort_t* T2H   = (ushort_t*)(ws + 5*S);
  ushort_t* T3H   = T2H + SSLOT;            // second half of slot 5
  float* SM  = ws + 9*S;
  float* pooled = SM;          // 4800
  float* KP     = SM + 4800;   // 4800
  float* VP     = SM + 9600;   // 4800
  float* KPN    = SM + 14400;  // 4800
  float* TAB    = SM + 19200;  // 16384
  float* RINV   = SM + 35584;  // 192
  float* SCA    = SM + 35776;  // 2304
  float* ACA    = SM + 38080;  // 2304
  ushort_t* WB  = (ushort_t*)(SM + 40960);  // 4*248832 bf16 weights (497664 floats)
  float* BNS    = SM + 40960 + 497664;      // 768 floats

  k_prep  <<<3888,  256, 0, stream>>>(w51a, w51b, w52a, w52b, WB);
  k_bnprep<<<1,     384, 0, stream>>>(bn51a, bn51b, bn52a, bn52b, BNS);
  k_ln    <<<100,   256, 0, stream>>>(x, nw, nb, XN);
  k_qkvv  <<<dim3(100,24), 256, 0, stream>>>(XN, wqkvv, Q);
  k_qs    <<<400,   256, 0, stream>>>(Q, temp, sls, qe, QN, QS);
  k_sr    <<<dim3(100,6),  256, 0, stream>>>(XN, srw, srb, XP2);
  k_pool  <<<4800,  64,  0, stream>>>(XP2, pooled);
  k_lnkv  <<<50,    256, 0, stream>>>(pooled, epaw, epab, wkv, KP, VP);
  k_kpn   <<<1,     256, 0, stream>>>(KP, KPN);
  k_tab   <<<4096,  512, 0, stream>>>(rct, c1w, c1b, c2w, c2b, TAB);
  k_attn  <<<NHh*NN, 64, 0, stream>>>(QS, QN, Kb, VSA, KPN, VP, TAB, rpi,
                                      rbl, ltok, lbias, XSA);
  k_canorm<<<192,   256, 0, stream>>>(Q, Kb, RINV);
  k_cascore<<<96,   256, 0, stream>>>(Q, Kb, SCA);
  k_casm  <<<1,     128, 0, stream>>>(SCA, RINV, temp2, ACA);
  k_caout <<<dim3(400,96), 64, 0, stream>>>(ACA, VCA, XCA);
  k_epa   <<<dim3(100,6),  256, 0, stream>>>(XSA, XCA, x, gamma, o1w, o1b, o2w, o2b,
                                             SKIPF, SKIPH);
  // resblock 1
  k_convm <<<400, 256, 0, stream>>>(SKIPH, WB,        BNS,     nullptr, T1H, nullptr);
  k_convm <<<400, 256, 0, stream>>>(T1H,   WB+WSZ,    BNS+192, SKIPF,   T2H, T2F);
  // resblock 2
  k_convm <<<400, 256, 0, stream>>>(T2H,   WB+2*WSZ,  BNS+384, nullptr, T1H, nullptr);
  k_convm <<<400, 256, 0, stream>>>(T1H,   WB+3*WSZ,  BNS+576, T2F,     T3H, nullptr);
  k_final <<<100, 256, 0, stream>>>(SKIPF, T3H, w8, b8, (float*)d_out);
}

// Round 4
// 669.572 us; speedup vs baseline: 3.3587x; 1.4050x over previous
//
#include <hip/hip_runtime.h>
#include <hip/hip_bf16.h>

// Problem constants
#define NN 25600      // D*H*W = 16*40*40 ; conv grid n = X*640+Y*16+Z, (X,Y,Z)=(40,40,16)
#define CC 96
#define NHh 4
#define HDd 24
#define SSLOT 2457600 // NN*CC floats per workspace slot
#define WSZ 248832    // 27*96*96 elems per conv weight tensor

typedef unsigned short ushort_t;
typedef float f32x4 __attribute__((ext_vector_type(4)));
typedef short s16x8 __attribute__((ext_vector_type(8)));

// All tensors are float32 on device (per reference dtypes).
__device__ __forceinline__ float LD(const void* p, int i){
  return ((const float*)p)[i];
}
__device__ __forceinline__ float b2f(ushort_t u){ return __uint_as_float(((unsigned)u)<<16); }
__device__ __forceinline__ ushort_t f2b(float f){   // RNE bf16 round
  unsigned u = __float_as_uint(f);
  unsigned r = (u + 0x7fffu + ((u>>16)&1u))>>16;
  return (ushort_t)r;
}

#define NEGINF (-3.0e38f)

// ---------------- K1: xt = x+1, LayerNorm over C -> XNH bf16 [n][96] ----------------
__global__ void k_ln(const void* __restrict__ x, const void* __restrict__ nw,
                     const void* __restrict__ nb, ushort_t* __restrict__ XNH){
  int n = blockIdx.x*256 + threadIdx.x;
  float s=0.f, ss=0.f;
  for(int c=0;c<CC;c++){ float v = LD(x, c*NN+n)+1.0f; s+=v; ss+=v*v; }
  float mu = s*(1.0f/CC);
  float var = ss*(1.0f/CC) - mu*mu;
  float inv = rsqrtf(var + 1e-5f);
  for(int c=0;c<CC;c++){
    float v = LD(x, c*NN+n)+1.0f;
    XNH[n*96+c] = f2b((v-mu)*inv*LD(nw,c) + LD(nb,c));
  }
}

// ---------------- prep: wqkvv/srw/w8 f32 -> bf16 (row-major [o][c]) ----------------
__global__ void k_prepw(const void* wq, const void* wsr, const void* w8,
                        ushort_t* __restrict__ WQH, ushort_t* __restrict__ WSH,
                        ushort_t* __restrict__ W8H){
  int e = blockIdx.x*256 + threadIdx.x;
  if(e < 36864) WQH[e] = f2b(LD(wq,e));
  if(e < 9216){ WSH[e] = f2b(LD(wsr,e)); W8H[e] = f2b(LD(w8,e)); }
}

// ---------------- K2: qkvv MFMA GEMM -> Q/K/VCA/VSA f32 [h][n][d] ----------------
// Block: 64 n, 4 waves x 16 n each; blockIdx.y picks 192 of 384 output rows.
__global__ __launch_bounds__(256,2) void k_qkvvm(
    const ushort_t* __restrict__ XNH, const ushort_t* __restrict__ WQH,
    float* __restrict__ out){ // out = Q base; slots s*SSLOT
  int tid=threadIdx.x, w=tid>>6, lane=tid&63, lan=lane&15, grp=lane>>4;
  int n = blockIdx.x*64 + w*16 + lan;
  int ybase = blockIdx.y*192;
  const ushort_t* bp = XNH + n*96;
  f32x4 acc[12];
  #pragma unroll
  for(int mt=0;mt<12;mt++) acc[mt] = (f32x4)(0.f);
  #pragma unroll
  for(int s=0;s<3;s++){
    s16x8 b = *reinterpret_cast<const s16x8*>(bp + s*32 + grp*8);
    #pragma unroll
    for(int mt=0;mt<12;mt++){
      s16x8 a = *reinterpret_cast<const s16x8*>(WQH + (ybase+mt*16+lan)*96 + s*32 + grp*8);
      acc[mt] = __builtin_amdgcn_mfma_f32_16x16x32_bf16(a, b, acc[mt], 0,0,0);
    }
  }
  #pragma unroll
  for(int mt=0;mt<12;mt++){
    #pragma unroll
    for(int r=0;r<4;r++){
      int o = ybase + mt*16 + grp*4 + r;
      int sl = o/96, rr = o%96, h = rr/24, dd = rr%24;
      out[sl*SSLOT + (h*NN+n)*24 + dd] = acc[mt][r];
    }
  }
}

// ---------------- K4: sr MFMA GEMM + gelu -> XP2 f32 [c][n] ----------------
__global__ __launch_bounds__(256,2) void k_srm(
    const ushort_t* __restrict__ XNH, const ushort_t* __restrict__ WSH,
    const void* __restrict__ bias, float* __restrict__ XP2){
  int tid=threadIdx.x, w=tid>>6, lane=tid&63, lan=lane&15, grp=lane>>4;
  int n = blockIdx.x*64 + w*16 + lan;
  const ushort_t* bp = XNH + n*96;
  f32x4 acc[6];
  #pragma unroll
  for(int mt=0;mt<6;mt++) acc[mt] = (f32x4)(0.f);
  #pragma unroll
  for(int s=0;s<3;s++){
    s16x8 b = *reinterpret_cast<const s16x8*>(bp + s*32 + grp*8);
    #pragma unroll
    for(int mt=0;mt<6;mt++){
      s16x8 a = *reinterpret_cast<const s16x8*>(WSH + (mt*16+lan)*96 + s*32 + grp*8);
      acc[mt] = __builtin_amdgcn_mfma_f32_16x16x32_bf16(a, b, acc[mt], 0,0,0);
    }
  }
  #pragma unroll
  for(int mt=0;mt<6;mt++){
    #pragma unroll
    for(int r=0;r<4;r++){
      int o = mt*16 + grp*4 + r;
      float y = acc[mt][r] + LD(bias,o);
      y = 0.5f*y*(1.0f + erff(y*0.70710678118f));
      XP2[o*NN+n] = y;
    }
  }
}

// ---------------- K3: qn = l2(q), qs = (qn+qe)*softplus(T)*sls ----------------
__global__ void k_qs(const float* __restrict__ Q, const void* __restrict__ temp,
                     const void* __restrict__ sls, const void* __restrict__ qe,
                     float* __restrict__ QN, float* __restrict__ QS){
  int id = blockIdx.x*256 + threadIdx.x;
  if(id >= NHh*NN) return;
  int h = id/NN, n = id%NN;
  const float* qr = Q + (h*NN+n)*24;
  float qv[24]; float ss=0.f;
  #pragma unroll
  for(int d=0;d<24;d++){ qv[d]=qr[d]; ss+=qv[d]*qv[d]; }
  float inv = 1.0f/fmaxf(sqrtf(ss), 1e-12f);
  float t = LD(temp,h);
  float sp = log1pf(expf(t)) * LD(sls,0);
  #pragma unroll
  for(int d=0;d<24;d++){
    float qn = qv[d]*inv;
    QN[(h*NN+n)*24+d] = qn;
    QS[(h*NN+n)*24+d] = (qn + LD(qe, h*24+d))*sp;
  }
}

// ---------------- K5: 8x8x8 average pool over (X,Y,Z)=(40,40,16) view ----------------
__global__ void k_pool(const float* __restrict__ XP2, float* __restrict__ pooled){
  int bb = blockIdx.x;
  int c = bb % CC, p = bb / CC;
  int ph = p/10, pw = (p%10)/2, pd = p%2;
  float s = 0.f;
  for(int t=threadIdx.x; t<512; t+=64){
    int i=t>>6, j=(t>>3)&7, k=t&7;
    int m = (ph*8+i)*640 + (pw*8+j)*16 + (pd*8+k);
    s += XP2[c*NN+m];
  }
  #pragma unroll
  for(int off=32;off;off>>=1) s += __shfl_down(s, off);
  if(threadIdx.x==0) pooled[p*CC+c] = s*(1.0f/512.0f);
}

// ---------------- K5b: LN(pooled) then kv = xp @ w_kv^T -> KP/VP [h][p][d] ----------------
__global__ void k_lnkv(const float* __restrict__ pooled, const void* __restrict__ ew,
                       const void* __restrict__ eb, const void* __restrict__ wkv,
                       float* __restrict__ KP, float* __restrict__ VP){
  __shared__ float row[96], lnr[96], st[2];
  int p = blockIdx.x, t = threadIdx.x;
  if(t<96) row[t] = pooled[p*96+t];
  __syncthreads();
  if(t==0){
    float s=0.f, ss=0.f;
    for(int c=0;c<96;c++){ float v=row[c]; s+=v; ss+=v*v; }
    float mu=s*(1.0f/96.0f);
    float var=ss*(1.0f/96.0f)-mu*mu;
    st[0]=mu; st[1]=rsqrtf(var+1e-5f);
  }
  __syncthreads();
  if(t<96) lnr[t] = (row[t]-st[0])*st[1]*LD(ew,t) + LD(eb,t);
  __syncthreads();
  if(t<192){
    float a=0.f;
    for(int c=0;c<96;c++) a += LD(wkv, t*96+c)*lnr[c];
    int g=t/24, d=t%24;
    if(g<4) KP[(g*50+p)*24+d]=a;
    else    VP[((g-4)*50+p)*24+d]=a;
  }
}

// ---------------- K5c: k_pool l2-normalize over d ----------------
__global__ void k_kpn(const float* __restrict__ KP, float* __restrict__ KPN){
  int t = threadIdx.x;
  if(t>=200) return;
  const float* r = KP + t*24;
  float ss=0.f;
  #pragma unroll
  for(int d=0;d<24;d++) ss += r[d]*r[d];
  float inv = 1.0f/fmaxf(sqrtf(ss),1e-12f);
  #pragma unroll
  for(int d=0;d<24;d++) KPN[t*24+d] = r[d]*inv;
}

// ---------------- K6: cpb MLP -> tab[T][NH] ----------------
__global__ void k_tab(const void* __restrict__ rct, const void* __restrict__ w1,
                      const void* __restrict__ b1, const void* __restrict__ w2,
                      const void* __restrict__ b2, float* __restrict__ TAB){
  __shared__ float red[32];
  int tt = blockIdx.x, j = threadIdx.x;
  float r0=LD(rct,tt*3), r1=LD(rct,tt*3+1), r2=LD(rct,tt*3+2);
  float hj = r0*LD(w1,j*3) + r1*LD(w1,j*3+1) + r2*LD(w1,j*3+2) + LD(b1,j);
  hj = fmaxf(hj, 0.f);
  int lane=j&63, wid=j>>6;
  for(int h=0;h<4;h++){
    float v = hj*LD(w2, h*512+j);
    #pragma unroll
    for(int off=32;off;off>>=1) v += __shfl_down(v, off);
    if(lane==0) red[wid*4+h]=v;
  }
  __syncthreads();
  if(j<4){
    float s=0.f;
    for(int w=0;w<8;w++) s += red[w*4+j];
    TAB[tt*4+j] = s + LD(b2,j);
  }
}

// ---------------- K7: fused local+pool attention per (h,n), one wave/block ----------------
__global__ void k_attn(const float* __restrict__ QS, const float* __restrict__ QN,
                       const float* __restrict__ K,  const float* __restrict__ VSA,
                       const float* __restrict__ KPN,const float* __restrict__ VP,
                       const float* __restrict__ TAB,const int* __restrict__ rpi,
                       const void* __restrict__ rbl, const void* __restrict__ ltok,
                       const void* __restrict__ lbias, float* __restrict__ XSA){
  __shared__ float qsr[24], qnr[24], av[80], pv[80], lt[28];
  int bb = blockIdx.x;
  int h = bb % NHh, n = bb / NHh;
  int t = threadIdx.x;
  if(t<24){ qsr[t]=QS[(h*NN+n)*24+t]; qnr[t]=QN[(h*NN+n)*24+t]; }
  __syncthreads();
  int d0=n/1600, rr=n%1600, h0=rr/40, w0=rr%40;  // original (D,H,W) grid
  for(int key=t; key<77; key+=64){
    float a;
    if(key<27){
      int dz=key/9-1, dy=(key%9)/3-1, dxx=key%3-1;
      int z=d0+dz, y=h0+dy, x=w0+dxx;
      float l = LD(lbias, h*27+key);
      #pragma unroll
      for(int d=0;d<24;d++) l += qnr[d]*LD(ltok, (h*24+d)*27+key);
      lt[key]=l;
      if((unsigned)z<16u && (unsigned)y<40u && (unsigned)x<40u){
        int nb = n + dz*1600 + dy*40 + dxx;
        const float* kr = K + (h*NN+nb)*24;
        a = LD(rbl, h*27+key);
        #pragma unroll
        for(int d=0;d<24;d++) a += qsr[d]*kr[d];
      } else a = NEGINF;
    } else {
      int p = key-27;
      const float* kr = KPN + (h*50+p)*24;
      a = TAB[rpi[n*50+p]*4 + h];
      #pragma unroll
      for(int d=0;d<24;d++) a += qsr[d]*kr[d];
    }
    av[key]=a;
  }
  __syncthreads();
  float m = NEGINF;
  for(int i=0;i<77;i++) m = fmaxf(m, av[i]);
  for(int key=t; key<77; key+=64) pv[key] = __expf(av[key]-m);
  __syncthreads();
  float s=0.f;
  for(int i=0;i<77;i++) s += pv[i];
  float inv = 1.0f/s;
  if(t<24){
    float acc=0.f;
    for(int l=0;l<27;l++){
      int dz=l/9-1, dy=(l%9)/3-1, dxx=l%3-1;
      int z=d0+dz, y=h0+dy, x=w0+dxx;
      if((unsigned)z<16u && (unsigned)y<40u && (unsigned)x<40u){
        int nb = n + dz*1600 + dy*40 + dxx;
        acc += (pv[l]*inv + lt[l]) * VSA[(h*NN+nb)*24+t];
      }
    }
    for(int p=0;p<50;p++) acc += pv[27+p]*inv * VP[(h*50+p)*24+t];
    XSA[(h*24+t)*NN + n] = acc;
  }
}

// ---------------- K8a: cross-attn row norms over N for q and k ----------------
__global__ void k_canorm(const float* __restrict__ Q, const float* __restrict__ K,
                         float* __restrict__ RINV){
  __shared__ float red[4];
  int bb=blockIdx.x;
  int which=bb/96, cd=bb%96, h=cd/24, d=cd%24;
  const float* src = which? K : Q;
  float s=0.f;
  for(int n=threadIdx.x; n<NN; n+=256){ float v=src[(h*NN+n)*24+d]; s+=v*v; }
  #pragma unroll
  for(int off=32;off;off>>=1) s += __shfl_down(s, off);
  int lane=threadIdx.x&63, wid=threadIdx.x>>6;
  if(lane==0) red[wid]=s;
  __syncthreads();
  if(threadIdx.x==0){
    float tt = red[0]+red[1]+red[2]+red[3];
    RINV[bb] = 1.0f/fmaxf(sqrtf(tt),1e-12f);
  }
}

// ---------------- K8b: S[h][d][e] = sum_n q[h,n,d]*k[h,n,e] ----------------
__global__ void k_cascore(const float* __restrict__ Q, const float* __restrict__ K,
                          float* __restrict__ SCA){
  __shared__ float red[4*24];
  int bb=blockIdx.x, h=bb/24, d=bb%24;
  float acc[24];
  #pragma unroll
  for(int e=0;e<24;e++) acc[e]=0.f;
  for(int n=threadIdx.x; n<NN; n+=256){
    float qv = Q[(h*NN+n)*24+d];
    const float* kr = K + (h*NN+n)*24;
    #pragma unroll
    for(int e=0;e<24;e++) acc[e] += qv*kr[e];
  }
  int lane=threadIdx.x&63, wid=threadIdx.x>>6;
  #pragma unroll
  for(int e=0;e<24;e++){
    float v=acc[e];
    #pragma unroll
    for(int off=32;off;off>>=1) v += __shfl_down(v, off);
    if(lane==0) red[wid*24+e]=v;
  }
  __syncthreads();
  if(threadIdx.x<24){
    int e=threadIdx.x;
    SCA[(h*24+d)*24+e] = red[e]+red[24+e]+red[48+e]+red[72+e];
  }
}

// ---------------- K8c: a_ca = softmax(S*qinv*kinv*t2) over e ----------------
__global__ void k_casm(const float* __restrict__ SCA, const float* __restrict__ RINV,
                       const void* __restrict__ t2, float* __restrict__ ACA){
  int t=threadIdx.x;
  if(t>=96) return;
  int h=t/24, d=t%24;
  float tv = LD(t2,h);
  float qi = RINV[h*24+d];
  float v[24]; float m=NEGINF;
  #pragma unroll
  for(int e=0;e<24;e++){
    v[e] = SCA[(h*24+d)*24+e]*qi*RINV[96+h*24+e]*tv;
    m = fmaxf(m, v[e]);
  }
  float s=0.f;
  #pragma unroll
  for(int e=0;e<24;e++){ v[e]=__expf(v[e]-m); s+=v[e]; }
  float inv=1.0f/s;
  #pragma unroll
  for(int e=0;e<24;e++) ACA[(h*24+d)*24+e] = v[e]*inv;
}

// ---------------- K8d: x_ca[c][n] = sum_e A[h,d,e]*v_ca[h,n,e] ----------------
__global__ void k_caout(const float* __restrict__ ACA, const float* __restrict__ VCA,
                        float* __restrict__ XCA){
  int c = blockIdx.y, h=c/24, d=c%24;
  int n = blockIdx.x*64 + threadIdx.x;
  float ar[24];
  #pragma unroll
  for(int e=0;e<24;e++) ar[e] = ACA[(h*24+d)*24+e];
  const float* vr = VCA + (h*NN+n)*24;
  float a=0.f;
  #pragma unroll
  for(int e=0;e<24;e++) a += ar[e]*vr[e];
  XCA[c*NN+n] = a;
}

// ---------------- K9: epa proj + ax = xt + gamma*epa -> SKIPF f32[n][96] + SKIPH bf16[n][96] ----------------
__global__ void k_epa(const float* __restrict__ XSA, const float* __restrict__ XCA,
                      const void* __restrict__ x, const void* __restrict__ gamma,
                      const void* __restrict__ o1w, const void* __restrict__ o1b,
                      const void* __restrict__ o2w, const void* __restrict__ o2b,
                      float* __restrict__ SKIPF, ushort_t* __restrict__ SKIPH){
  int n = blockIdx.x*256 + threadIdx.x;
  int c0 = blockIdx.y*16;
  bool first = (c0 < 48);
  const float* src = first? XSA : XCA;
  const float* wp = (const float*)(first? o1w : o2w);
  const void* bb = first? o1b : o2b;
  int cb = first? c0 : c0-48;
  float acc[16];
  #pragma unroll
  for(int j=0;j<16;j++) acc[j]=0.f;
  for(int c=0;c<96;c+=4){
    float v0=src[(c+0)*NN+n], v1=src[(c+1)*NN+n], v2=src[(c+2)*NN+n], v3=src[(c+3)*NN+n];
    #pragma unroll
    for(int j=0;j<16;j++){
      const float4 wv = *reinterpret_cast<const float4*>(wp + (cb+j)*96 + c);
      acc[j] += wv.x*v0 + wv.y*v1 + wv.z*v2 + wv.w*v3;
    }
  }
  #pragma unroll
  for(int j=0;j<16;j++){
    int c = c0+j;
    float e = acc[j] + LD(bb, cb+j);
    float v = LD(x, c*NN+n) + 1.0f + LD(gamma,c)*e;
    SKIPF[n*96+c] = v;
    SKIPH[n*96+c] = f2b(v);
  }
}

// ---------------- prep: conv weights -> bf16 WB[t][tap][o][i] ----------------
__global__ void k_prep(const void* w0, const void* w1, const void* w2, const void* w3,
                       ushort_t* __restrict__ WB){
  int e = blockIdx.x*256 + threadIdx.x;
  if(e >= 4*WSZ) return;
  int t = e/WSZ, r = e%WSZ;
  int tap = r/9216, r2 = r%9216, o = r2/96, i = r2%96;
  const void* w = (t==0)? w0 : (t==1)? w1 : (t==2)? w2 : w3;
  WB[e] = f2b(LD(w, (o*96+i)*27 + tap));
}

// ---------------- prep: BN scale/shift per conv: BNS[t*192 + {o, 96+o}] ----------------
__global__ void k_bnprep(const void* b0, const void* b1, const void* b2, const void* b3,
                         float* __restrict__ BNS){
  int id = threadIdx.x;
  if(id >= 384) return;
  int t = id/96, o = id%96;
  const void* bn = (t==0)? b0 : (t==1)? b1 : (t==2)? b2 : b3;
  float g=LD(bn,o), b=LD(bn,96+o), mu=LD(bn,192+o), var=LD(bn,288+o);
  float s = g*rsqrtf(var+1e-5f);
  BNS[t*192+o] = s;
  BNS[t*192+96+o] = b - mu*s;
}

// ---------------- K10: MFMA implicit-GEMM conv3x3x3 + BN + res + lrelu ----------------
// Block: 64 n x 96 o, 4 waves split the 27 taps (K-split), LDS reduce.
__global__ __launch_bounds__(256,2) void k_convm(
    const ushort_t* __restrict__ IN,   // bf16 [n][96]
    const ushort_t* __restrict__ WB,   // bf16 [27][96][96] (o-major, i contiguous)
    const float* __restrict__ BNS,     // [192] scale|shift
    const float* __restrict__ resf,    // f32 [n][96] or null
    ushort_t* __restrict__ outh,       // bf16 [n][96]
    float* __restrict__ outf)          // f32 [n][96] or null
{
  __shared__ float red[4][48][68];   // 52.2 KB -> 2 blocks/CU
  int tid = threadIdx.x;
  int w = tid>>6, lane = tid&63;
  int lan = lane&15, grp = lane>>4;
  int n0 = blockIdx.x*64;

  int nj[4], Xj[4], Yj[4], Zj[4];
  #pragma unroll
  for(int j=0;j<4;j++){
    int n = n0 + j*16 + lan;
    nj[j]=n; Xj[j]=n/640; int rr=n%640; Yj[j]=rr/16; Zj[j]=rr&15;
  }

  f32x4 acc[6][4];
  #pragma unroll
  for(int mt=0;mt<6;mt++)
    #pragma unroll
    for(int j=0;j<4;j++) acc[mt][j] = (f32x4)(0.f);

  int lo = (w*27)>>2, hi = ((w+1)*27)>>2;   // 6,7,7,7 taps
  for(int tap=lo; tap<hi; ++tap){
    int dx=tap/9-1, dy=(tap%9)/3-1, dz=tap%3-1;
    int off = dx*640 + dy*16 + dz;
    const ushort_t* wt = WB + tap*9216;
    const ushort_t* sp[4]; bool ok[4];
    #pragma unroll
    for(int j=0;j<4;j++){
      ok[j] = (unsigned)(Xj[j]+dx)<40u && (unsigned)(Yj[j]+dy)<40u && (unsigned)(Zj[j]+dz)<16u;
      sp[j] = IN + (nj[j]+off)*96 + grp*8;
    }
    #pragma unroll
    for(int s=0;s<3;s++){
      s16x8 a[6];
      #pragma unroll
      for(int mt=0;mt<6;mt++)
        a[mt] = *reinterpret_cast<const s16x8*>(wt + (mt*16+lan)*96 + s*32 + grp*8);
      #pragma unroll
      for(int j=0;j<4;j++){
        s16x8 b = {};
        if(ok[j]) b = *reinterpret_cast<const s16x8*>(sp[j] + s*32);
        #pragma unroll
        for(int mt=0;mt<6;mt++)
          acc[mt][j] = __builtin_amdgcn_mfma_f32_16x16x32_bf16(a[mt], b, acc[mt][j], 0,0,0);
      }
    }
  }

  // cross-wave reduce (2 chunks of 48 o) + fused epilogue
  int n_loc = tid&63;
  int ob = (tid>>6)*12;
  int n = n0 + n_loc;
  #pragma unroll
  for(int chunk=0; chunk<2; ++chunk){
    if(chunk) __syncthreads();
    #pragma unroll
    for(int m=0;m<3;m++){
      int mt = chunk*3+m;
      #pragma unroll
      for(int j=0;j<4;j++)
        #pragma unroll
        for(int r=0;r<4;r++)
          red[w][m*16 + grp*4 + r][j*16 + lan] = acc[mt][j][r];
    }
    __syncthreads();
    #pragma unroll
    for(int q=0;q<12;q++){
      int o = ob+q;
      float v = red[0][o][n_loc]+red[1][o][n_loc]+red[2][o][n_loc]+red[3][o][n_loc];
      int og = chunk*48 + o;
      v = v*BNS[og] + BNS[96+og];
      if(resf) v += resf[n*96+og];
      v = (v>=0.f)? v : 0.01f*v;
      if(outf) outf[n*96+og] = v;
      outh[n*96+og] = f2b(v);
    }
  }
}

// ---------------- K11: MFMA final: out[c][n] = skipf[n][c] + conv8(T3h)[c][n] + b8[c] ----------------
__global__ __launch_bounds__(256,2) void k_finm(
    const float* __restrict__ SKIPF, const ushort_t* __restrict__ T3H,
    const ushort_t* __restrict__ W8H, const void* __restrict__ b,
    float* __restrict__ out){
  int tid=threadIdx.x, w=tid>>6, lane=tid&63, lan=lane&15, grp=lane>>4;
  int n = blockIdx.x*64 + w*16 + lan;
  const ushort_t* bp = T3H + n*96;
  f32x4 acc[6];
  #pragma unroll
  for(int mt=0;mt<6;mt++) acc[mt] = (f32x4)(0.f);
  #pragma unroll
  for(int s=0;s<3;s++){
    s16x8 bb = *reinterpret_cast<const s16x8*>(bp + s*32 + grp*8);
    #pragma unroll
    for(int mt=0;mt<6;mt++){
      s16x8 a = *reinterpret_cast<const s16x8*>(W8H + (mt*16+lan)*96 + s*32 + grp*8);
      acc[mt] = __builtin_amdgcn_mfma_f32_16x16x32_bf16(a, bb, acc[mt], 0,0,0);
    }
  }
  #pragma unroll
  for(int mt=0;mt<6;mt++){
    #pragma unroll
    for(int r=0;r<4;r++){
      int o = mt*16 + grp*4 + r;
      out[o*NN+n] = SKIPF[n*96+o] + acc[mt][r] + LD(b,o);
    }
  }
}

extern "C" void kernel_launch(void* const* d_in, const int* in_sizes, int n_in,
                              void* d_out, int out_size, void* d_ws, size_t ws_size,
                              hipStream_t stream){
  const void* x     = d_in[0];
  const int*  rpi   = (const int*)d_in[1];
  const void* rct   = d_in[2];
  const void* sls   = d_in[3];
  const void* nw    = d_in[4];
  const void* nb    = d_in[5];
  const void* gamma = d_in[6];
  const void* wqkvv = d_in[7];
  const void* temp  = d_in[8];
  const void* temp2 = d_in[9];
  const void* qe    = d_in[10];
  const void* rbl   = d_in[11];
  const void* ltok  = d_in[12];
  const void* lbias = d_in[13];
  const void* srw   = d_in[14];
  const void* srb   = d_in[15];
  const void* epaw  = d_in[16];
  const void* epab  = d_in[17];
  const void* wkv   = d_in[18];
  const void* c1w   = d_in[19];
  const void* c1b   = d_in[20];
  const void* c2w   = d_in[21];
  const void* c2b   = d_in[22];
  const void* o1w   = d_in[23];
  const void* o1b   = d_in[24];
  const void* o2w   = d_in[25];
  const void* o2b   = d_in[26];
  const void* w51a  = d_in[27];
  const void* bn51a = d_in[28];
  const void* w51b  = d_in[29];
  const void* bn51b = d_in[30];
  const void* w52a  = d_in[31];
  const void* bn52a = d_in[32];
  const void* w52b  = d_in[33];
  const void* bn52b = d_in[34];
  const void* w8    = d_in[35];
  const void* b8    = d_in[36];

  float* ws = (float*)d_ws;
  const size_t S = SSLOT;
  // f32 slots (lifetimes verified against launch order)
  ushort_t* XNH = (ushort_t*)ws; // slot 0 first half; dead after k_srm -> SKIPF
  float* SKIPF = ws;             // written by k_epa (after XNH dead)
  float* Q     = ws + 1*S;    // dead after k_cascore
  float* Kb    = ws + 2*S;    // dead after k_cascore -> T2F
  float* T2F   = ws + 2*S;
  float* VCA   = ws + 3*S;    // dead after k_caout
  float* VSA   = ws + 4*S;    // dead after k_attn -> SKIPH/T1H (bf16)
  float* QN    = ws + 5*S;    // dead after k_attn -> T2H/T3H (bf16)
  float* QS    = ws + 6*S;    // dead after k_attn
  float* XP2   = ws + 7*S;    // dead after k_pool -> XSA
  float* XSA   = ws + 7*S;
  float* XCA   = ws + 8*S;
  ushort_t* SKIPH = (ushort_t*)(ws + 4*S);
  ushort_t* T1H   = SKIPH + SSLOT;          // second half of slot 4
  ushort_t* T2H   = (ushort_t*)(ws + 5*S);
  ushort_t* T3H   = T2H + SSLOT;            // second half of slot 5
  float* SM  = ws + 9*S;
  float* pooled = SM;          // 4800
  float* KP     = SM + 4800;   // 4800
  float* VP     = SM + 9600;   // 4800
  float* KPN    = SM + 14400;  // 4800
  float* TAB    = SM + 19200;  // 16384
  float* RINV   = SM + 35584;  // 192
  float* SCA    = SM + 35776;  // 2304
  float* ACA    = SM + 38080;  // 2304
  ushort_t* WB  = (ushort_t*)(SM + 40960);  // 4*248832 bf16 weights (497664 floats)
  float* BNS    = SM + 40960 + 497664;      // 768 floats
  ushort_t* WQH = (ushort_t*)(BNS + 768);   // 36864 bf16 (18432 f)
  ushort_t* WSH = WQH + 36864;              // 9216 bf16
  ushort_t* W8H = WSH + 9216;               // 9216 bf16

  k_prep  <<<3888,  256, 0, stream>>>(w51a, w51b, w52a, w52b, WB);
  k_bnprep<<<1,     384, 0, stream>>>(bn51a, bn51b, bn52a, bn52b, BNS);
  k_prepw <<<144,   256, 0, stream>>>(wqkvv, srw, w8, WQH, WSH, W8H);
  k_ln    <<<100,   256, 0, stream>>>(x, nw, nb, XNH);
  k_qkvvm <<<dim3(400,2), 256, 0, stream>>>(XNH, WQH, Q);
  k_qs    <<<400,   256, 0, stream>>>(Q, temp, sls, qe, QN, QS);
  k_srm   <<<400,   256, 0, stream>>>(XNH, WSH, srb, XP2);
  k_pool  <<<4800,  64,  0, stream>>>(XP2, pooled);
  k_lnkv  <<<50,    256, 0, stream>>>(pooled, epaw, epab, wkv, KP, VP);
  k_kpn   <<<1,     256, 0, stream>>>(KP, KPN);
  k_tab   <<<4096,  512, 0, stream>>>(rct, c1w, c1b, c2w, c2b, TAB);
  k_attn  <<<NHh*NN, 64, 0, stream>>>(QS, QN, Kb, VSA, KPN, VP, TAB, rpi,
                                      rbl, ltok, lbias, XSA);
  k_canorm<<<192,   256, 0, stream>>>(Q, Kb, RINV);
  k_cascore<<<96,   256, 0, stream>>>(Q, Kb, SCA);
  k_casm  <<<1,     128, 0, stream>>>(SCA, RINV, temp2, ACA);
  k_caout <<<dim3(400,96), 64, 0, stream>>>(ACA, VCA, XCA);
  k_epa   <<<dim3(100,6),  256, 0, stream>>>(XSA, XCA, x, gamma, o1w, o1b, o2w, o2b,
                                             SKIPF, SKIPH);
  // resblock 1
  k_convm <<<400, 256, 0, stream>>>(SKIPH, WB,        BNS,     nullptr, T1H, nullptr);
  k_convm <<<400, 256, 0, stream>>>(T1H,   WB+WSZ,    BNS+192, SKIPF,   T2H, T2F);
  // resblock 2
  k_convm <<<400, 256, 0, stream>>>(T2H,   WB+2*WSZ,  BNS+384, nullptr, T1H, nullptr);
  k_convm <<<400, 256, 0, stream>>>(T1H,   WB+3*WSZ,  BNS+576, T2F,     T3H, nullptr);
  k_finm  <<<400, 256, 0, stream>>>(SKIPF, T3H, W8H, b8, (float*)d_out);
}

// Round 5
// 602.908 us; speedup vs baseline: 3.7300x; 1.1106x over previous
//
#include <hip/hip_runtime.h>
#include <hip/hip_bf16.h>

// Problem constants
#define NN 25600      // D*H*W = 16*40*40 ; attn grid n = d0*1600 + h0*40 + w0
#define CC 96
#define NHh 4
#define HDd 24
#define SSLOT 2457600 // NN*CC floats per workspace slot
#define WSZ 248832    // 27*96*96 elems per conv weight tensor

typedef unsigned short ushort_t;
typedef float f32x4 __attribute__((ext_vector_type(4)));
typedef short s16x8 __attribute__((ext_vector_type(8)));

// All tensors are float32 on device (per reference dtypes).
__device__ __forceinline__ float LD(const void* p, int i){
  return ((const float*)p)[i];
}
__device__ __forceinline__ float b2f(ushort_t u){ return __uint_as_float(((unsigned)u)<<16); }
__device__ __forceinline__ ushort_t f2b(float f){   // RNE bf16 round
  unsigned u = __float_as_uint(f);
  unsigned r = (u + 0x7fffu + ((u>>16)&1u))>>16;
  return (ushort_t)r;
}

#define NEGINF (-3.0e38f)

// ---------------- K1: xt = x+1, LayerNorm over C -> XNH bf16 [n][96] ----------------
__global__ void k_ln(const void* __restrict__ x, const void* __restrict__ nw,
                     const void* __restrict__ nb, ushort_t* __restrict__ XNH){
  int n = blockIdx.x*256 + threadIdx.x;
  float s=0.f, ss=0.f;
  for(int c=0;c<CC;c++){ float v = LD(x, c*NN+n)+1.0f; s+=v; ss+=v*v; }
  float mu = s*(1.0f/CC);
  float var = ss*(1.0f/CC) - mu*mu;
  float inv = rsqrtf(var + 1e-5f);
  for(int c=0;c<CC;c++){
    float v = LD(x, c*NN+n)+1.0f;
    XNH[n*96+c] = f2b((v-mu)*inv*LD(nw,c) + LD(nb,c));
  }
}

// ---------------- prep: wqkvv/srw/w8 f32 -> bf16 (row-major [o][c]) ----------------
__global__ void k_prepw(const void* wq, const void* wsr, const void* w8,
                        ushort_t* __restrict__ WQH, ushort_t* __restrict__ WSH,
                        ushort_t* __restrict__ W8H){
  int e = blockIdx.x*256 + threadIdx.x;
  if(e < 36864) WQH[e] = f2b(LD(wq,e));
  if(e < 9216){ WSH[e] = f2b(LD(wsr,e)); W8H[e] = f2b(LD(w8,e)); }
}

// ---------------- prep: rpi [n][50] -> rpiT [50][n] (coalesced gather in attn) -------
__global__ void k_rpit(const int* __restrict__ rpi, int* __restrict__ rpiT){
  int e = blockIdx.x*256 + threadIdx.x;
  if(e >= 50*NN) return;
  int p = e/NN, n = e%NN;
  rpiT[e] = rpi[n*50+p];
}

// ---------------- K2: qkvv MFMA GEMM -> Q/K/VCA/VSA f32 [h][n][d] ----------------
__global__ __launch_bounds__(256,2) void k_qkvvm(
    const ushort_t* __restrict__ XNH, const ushort_t* __restrict__ WQH,
    float* __restrict__ out){ // out = Q base; slots s*SSLOT
  int tid=threadIdx.x, w=tid>>6, lane=tid&63, lan=lane&15, grp=lane>>4;
  int n = blockIdx.x*64 + w*16 + lan;
  int ybase = blockIdx.y*192;
  const ushort_t* bp = XNH + n*96;
  f32x4 acc[12];
  #pragma unroll
  for(int mt=0;mt<12;mt++) acc[mt] = (f32x4)(0.f);
  #pragma unroll
  for(int s=0;s<3;s++){
    s16x8 b = *reinterpret_cast<const s16x8*>(bp + s*32 + grp*8);
    #pragma unroll
    for(int mt=0;mt<12;mt++){
      s16x8 a = *reinterpret_cast<const s16x8*>(WQH + (ybase+mt*16+lan)*96 + s*32 + grp*8);
      acc[mt] = __builtin_amdgcn_mfma_f32_16x16x32_bf16(a, b, acc[mt], 0,0,0);
    }
  }
  #pragma unroll
  for(int mt=0;mt<12;mt++){
    #pragma unroll
    for(int r=0;r<4;r++){
      int o = ybase + mt*16 + grp*4 + r;
      int sl = o/96, rr = o%96, h = rr/24, dd = rr%24;
      out[sl*SSLOT + (h*NN+n)*24 + dd] = acc[mt][r];
    }
  }
}

// ---------------- K4: sr MFMA GEMM + gelu -> XP2 f32 [c][n] ----------------
__global__ __launch_bounds__(256,2) void k_srm(
    const ushort_t* __restrict__ XNH, const ushort_t* __restrict__ WSH,
    const void* __restrict__ bias, float* __restrict__ XP2){
  int tid=threadIdx.x, w=tid>>6, lane=tid&63, lan=lane&15, grp=lane>>4;
  int n = blockIdx.x*64 + w*16 + lan;
  const ushort_t* bp = XNH + n*96;
  f32x4 acc[6];
  #pragma unroll
  for(int mt=0;mt<6;mt++) acc[mt] = (f32x4)(0.f);
  #pragma unroll
  for(int s=0;s<3;s++){
    s16x8 b = *reinterpret_cast<const s16x8*>(bp + s*32 + grp*8);
    #pragma unroll
    for(int mt=0;mt<6;mt++){
      s16x8 a = *reinterpret_cast<const s16x8*>(WSH + (mt*16+lan)*96 + s*32 + grp*8);
      acc[mt] = __builtin_amdgcn_mfma_f32_16x16x32_bf16(a, b, acc[mt], 0,0,0);
    }
  }
  #pragma unroll
  for(int mt=0;mt<6;mt++){
    #pragma unroll
    for(int r=0;r<4;r++){
      int o = mt*16 + grp*4 + r;
      float y = acc[mt][r] + LD(bias,o);
      y = 0.5f*y*(1.0f + erff(y*0.70710678118f));
      XP2[o*NN+n] = y;
    }
  }
}

// ---------------- K3: qn = l2(q), qs = (qn+qe)*softplus(T)*sls ----------------
__global__ void k_qs(const float* __restrict__ Q, const void* __restrict__ temp,
                     const void* __restrict__ sls, const void* __restrict__ qe,
                     float* __restrict__ QN, float* __restrict__ QS){
  int id = blockIdx.x*256 + threadIdx.x;
  if(id >= NHh*NN) return;
  int h = id/NN, n = id%NN;
  const float* qr = Q + (h*NN+n)*24;
  float qv[24]; float ss=0.f;
  #pragma unroll
  for(int d=0;d<24;d++){ qv[d]=qr[d]; ss+=qv[d]*qv[d]; }
  float inv = 1.0f/fmaxf(sqrtf(ss), 1e-12f);
  float t = LD(temp,h);
  float sp = log1pf(expf(t)) * LD(sls,0);
  #pragma unroll
  for(int d=0;d<24;d++){
    float qn = qv[d]*inv;
    QN[(h*NN+n)*24+d] = qn;
    QS[(h*NN+n)*24+d] = (qn + LD(qe, h*24+d))*sp;
  }
}

// ---------------- K5: 8x8x8 average pool over (X,Y,Z)=(40,40,16) view ----------------
__global__ void k_pool(const float* __restrict__ XP2, float* __restrict__ pooled){
  int bb = blockIdx.x;
  int c = bb % CC, p = bb / CC;
  int ph = p/10, pw = (p%10)/2, pd = p%2;
  float s = 0.f;
  for(int t=threadIdx.x; t<512; t+=64){
    int i=t>>6, j=(t>>3)&7, k=t&7;
    int m = (ph*8+i)*640 + (pw*8+j)*16 + (pd*8+k);
    s += XP2[c*NN+m];
  }
  #pragma unroll
  for(int off=32;off;off>>=1) s += __shfl_down(s, off);
  if(threadIdx.x==0) pooled[p*CC+c] = s*(1.0f/512.0f);
}

// ---------------- K5b: LN(pooled) then kv = xp @ w_kv^T -> KP/VP [h][p][d] ----------------
__global__ void k_lnkv(const float* __restrict__ pooled, const void* __restrict__ ew,
                       const void* __restrict__ eb, const void* __restrict__ wkv,
                       float* __restrict__ KP, float* __restrict__ VP){
  __shared__ float row[96], lnr[96], st[2];
  int p = blockIdx.x, t = threadIdx.x;
  if(t<96) row[t] = pooled[p*96+t];
  __syncthreads();
  if(t==0){
    float s=0.f, ss=0.f;
    for(int c=0;c<96;c++){ float v=row[c]; s+=v; ss+=v*v; }
    float mu=s*(1.0f/96.0f);
    float var=ss*(1.0f/96.0f)-mu*mu;
    st[0]=mu; st[1]=rsqrtf(var+1e-5f);
  }
  __syncthreads();
  if(t<96) lnr[t] = (row[t]-st[0])*st[1]*LD(ew,t) + LD(eb,t);
  __syncthreads();
  if(t<192){
    float a=0.f;
    for(int c=0;c<96;c++) a += LD(wkv, t*96+c)*lnr[c];
    int g=t/24, d=t%24;
    if(g<4) KP[(g*50+p)*24+d]=a;
    else    VP[((g-4)*50+p)*24+d]=a;
  }
}

// ---------------- K5c: k_pool l2-normalize over d ----------------
__global__ void k_kpn(const float* __restrict__ KP, float* __restrict__ KPN){
  int t = threadIdx.x;
  if(t>=200) return;
  const float* r = KP + t*24;
  float ss=0.f;
  #pragma unroll
  for(int d=0;d<24;d++) ss += r[d]*r[d];
  float inv = 1.0f/fmaxf(sqrtf(ss),1e-12f);
  #pragma unroll
  for(int d=0;d<24;d++) KPN[t*24+d] = r[d]*inv;
}

// ---------------- K6: cpb MLP -> tab[T][NH] ----------------
__global__ void k_tab(const void* __restrict__ rct, const void* __restrict__ w1,
                      const void* __restrict__ b1, const void* __restrict__ w2,
                      const void* __restrict__ b2, float* __restrict__ TAB){
  __shared__ float red[32];
  int tt = blockIdx.x, j = threadIdx.x;
  float r0=LD(rct,tt*3), r1=LD(rct,tt*3+1), r2=LD(rct,tt*3+2);
  float hj = r0*LD(w1,j*3) + r1*LD(w1,j*3+1) + r2*LD(w1,j*3+2) + LD(b1,j);
  hj = fmaxf(hj, 0.f);
  int lane=j&63, wid=j>>6;
  for(int h=0;h<4;h++){
    float v = hj*LD(w2, h*512+j);
    #pragma unroll
    for(int off=32;off;off>>=1) v += __shfl_down(v, off);
    if(lane==0) red[wid*4+h]=v;
  }
  __syncthreads();
  if(j<4){
    float s=0.f;
    for(int w=0;w<8;w++) s += red[w*4+j];
    TAB[tt*4+j] = s + LD(b2,j);
  }
}

// ---------------- K7: LDS-tiled local+pool attention ----------------
// Block = 1 wave = 64 queries (8 h0 x 8 w0 at fixed d0); grid (400 tiles, 4 heads).
__global__ __launch_bounds__(64) void k_attn2(
    const float* __restrict__ QS, const float* __restrict__ QN,
    const float* __restrict__ K,  const float* __restrict__ VSA,
    const float* __restrict__ KPN,const float* __restrict__ VP,
    const float* __restrict__ TAB,const int* __restrict__ rpiT,
    const void* __restrict__ rbl, const void* __restrict__ ltok,
    const void* __restrict__ lbias, float* __restrict__ XSA)
{
  __shared__ float KV[300*25];   // 30 KB, rows padded to 25 (bank-friendly)
  int tile = blockIdx.x, h = blockIdx.y;
  int d0 = tile/25, hg = (tile%25)/5, wg = tile%5;
  int lane = threadIdx.x, hy = lane>>3, wx = lane&7;
  int h0 = hg*8+hy, w0 = wg*8+wx;
  int n = d0*1600 + h0*40 + w0;

  // ---- stage K halo (300 rows x 24 f32, coalesced float4) ----
  const float* Kh = K + (size_t)h*NN*24;
  for(int f=lane; f<1800; f+=64){
    int row = f/6, q = f%6;
    int dr = row/100, yr = (row%100)/10, xr = row%10;
    int zc = min(max(d0+dr-1,0),15), yc = min(max(hg*8+yr-1,0),39), xc = min(max(wg*8+xr-1,0),39);
    float4 v = *reinterpret_cast<const float4*>(Kh + (zc*1600+yc*40+xc)*24 + q*4);
    *reinterpret_cast<float4*>(KV + row*25 + q*4) = v;
  }

  // ---- lt[k] = lbias + qn . ltok (ltok loads are wave-uniform) ----
  float lt[27];
  {
    float qn[24];
    const float* qnp = QN + ((size_t)h*NN+n)*24;
    #pragma unroll
    for(int d=0; d<24; d+=4){
      float4 a = *reinterpret_cast<const float4*>(qnp+d);
      qn[d]=a.x; qn[d+1]=a.y; qn[d+2]=a.z; qn[d+3]=a.w;
    }
    #pragma unroll
    for(int k=0;k<27;k++) lt[k] = LD(lbias, h*27+k);
    #pragma unroll
    for(int d=0; d<24; d++){
      float q = qn[d];
      #pragma unroll
      for(int k=0;k<27;k++) lt[k] += q*LD(ltok, (h*24+d)*27+k);
    }
  }

  float qs[24];
  const float* qsp = QS + ((size_t)h*NN+n)*24;
  #pragma unroll
  for(int d=0; d<24; d+=4){
    float4 a = *reinterpret_cast<const float4*>(qsp+d);
    qs[d]=a.x; qs[d+1]=a.y; qs[d+2]=a.z; qs[d+3]=a.w;
  }

  __syncthreads();

  // ---- scores: 27 local (LDS) + 50 pool (uniform KPN) ----
  float av[77];
  #pragma unroll
  for(int k=0;k<27;k++){
    int kz=k/9, ky=(k%9)/3, kx=k%3;
    bool ok = (unsigned)(d0+kz-1)<16u && (unsigned)(h0+ky-1)<40u && (unsigned)(w0+kx-1)<40u;
    float sc = NEGINF;
    if(ok){
      const float* kr = KV + (kz*100 + (hy+ky)*10 + (wx+kx))*25;
      sc = LD(rbl, h*27+k);
      #pragma unroll
      for(int d=0;d<24;d+=4){
        float4 kv = *reinterpret_cast<const float4*>(kr+d);
        sc += qs[d]*kv.x + qs[d+1]*kv.y + qs[d+2]*kv.z + qs[d+3]*kv.w;
      }
    }
    av[k]=sc;
  }
  #pragma unroll
  for(int p=0;p<50;p++){
    const float* kr = KPN + ((size_t)h*50+p)*24;
    float sc = TAB[rpiT[(size_t)p*NN+n]*4 + h];
    #pragma unroll
    for(int d=0;d<24;d+=4){
      float4 kv = *reinterpret_cast<const float4*>(kr+d);
      sc += qs[d]*kv.x + qs[d+1]*kv.y + qs[d+2]*kv.z + qs[d+3]*kv.w;
    }
    av[27+p]=sc;
  }

  // ---- softmax over 77 (registers) ----
  float m = av[0];
  #pragma unroll
  for(int k=1;k<77;k++) m = fmaxf(m, av[k]);
  float s = 0.f;
  #pragma unroll
  for(int k=0;k<77;k++){ av[k] = __expf(av[k]-m); s += av[k]; }
  float inv = 1.0f/s;

  // ---- restage V over K ----
  __syncthreads();
  const float* Vh = VSA + (size_t)h*NN*24;
  for(int f=lane; f<1800; f+=64){
    int row = f/6, q = f%6;
    int dr = row/100, yr = (row%100)/10, xr = row%10;
    int zc = min(max(d0+dr-1,0),15), yc = min(max(hg*8+yr-1,0),39), xc = min(max(wg*8+xr-1,0),39);
    float4 v = *reinterpret_cast<const float4*>(Vh + (zc*1600+yc*40+xc)*24 + q*4);
    *reinterpret_cast<float4*>(KV + row*25 + q*4) = v;
  }
  __syncthreads();

  // ---- PV accumulate ----
  float acc[24];
  #pragma unroll
  for(int d=0;d<24;d++) acc[d]=0.f;
  #pragma unroll
  for(int k=0;k<27;k++){
    int kz=k/9, ky=(k%9)/3, kx=k%3;
    bool ok = (unsigned)(d0+kz-1)<16u && (unsigned)(h0+ky-1)<40u && (unsigned)(w0+kx-1)<40u;
    if(ok){
      float wgt = av[k]*inv + lt[k];
      const float* vr = KV + (kz*100 + (hy+ky)*10 + (wx+kx))*25;
      #pragma unroll
      for(int d=0;d<24;d+=4){
        float4 vv = *reinterpret_cast<const float4*>(vr+d);
        acc[d] += wgt*vv.x; acc[d+1] += wgt*vv.y; acc[d+2] += wgt*vv.z; acc[d+3] += wgt*vv.w;
      }
    }
  }
  #pragma unroll
  for(int p=0;p<50;p++){
    float wgt = av[27+p]*inv;
    const float* vr = VP + ((size_t)h*50+p)*24;
    #pragma unroll
    for(int d=0;d<24;d+=4){
      float4 vv = *reinterpret_cast<const float4*>(vr+d);
      acc[d] += wgt*vv.x; acc[d+1] += wgt*vv.y; acc[d+2] += wgt*vv.z; acc[d+3] += wgt*vv.w;
    }
  }
  #pragma unroll
  for(int d=0;d<24;d++)
    XSA[((size_t)h*24+d)*NN + n] = acc[d];
}

// ---------------- K8a+b: cross-attn scores + norms, split-K over n (8 chunks) -------
__global__ void k_cascore2(const float* __restrict__ Q, const float* __restrict__ K,
                           float* __restrict__ PAR){
  __shared__ float red[4][26];
  int hd = blockIdx.x, h = hd/24, d = hd%24;
  int n0 = blockIdx.y*3200;
  float acc[24]; float qss=0.f, kss=0.f;
  #pragma unroll
  for(int e=0;e<24;e++) acc[e]=0.f;
  for(int i=threadIdx.x; i<3200; i+=256){
    int n = n0 + i;
    const float* kr = K + ((size_t)h*NN+n)*24;
    float qv = Q[((size_t)h*NN+n)*24+d];
    qss += qv*qv;
    float kd = kr[d]; kss += kd*kd;
    #pragma unroll
    for(int e=0;e<24;e++) acc[e] += qv*kr[e];
  }
  int lane=threadIdx.x&63, wid=threadIdx.x>>6;
  #pragma unroll
  for(int j=0;j<26;j++){
    float v = (j<24)? acc[j] : (j==24? qss : kss);
    #pragma unroll
    for(int off=32;off;off>>=1) v += __shfl_down(v, off);
    if(lane==0) red[wid][j]=v;
  }
  __syncthreads();
  if(threadIdx.x<26){
    int j=threadIdx.x;
    PAR[((size_t)blockIdx.y*96+hd)*26 + j] = red[0][j]+red[1][j]+red[2][j]+red[3][j];
  }
}

// ---------------- K8c: reduce partials, softmax -> ACA ----------------
__global__ void k_casm2(const float* __restrict__ PAR, const void* __restrict__ t2,
                        float* __restrict__ ACA){
  __shared__ float kinv_s[96];
  int t = threadIdx.x;  // blockDim = 96
  int h = t/24;
  float S[24]; float qss=0.f, kss=0.f;
  #pragma unroll
  for(int e=0;e<24;e++) S[e]=0.f;
  for(int c=0;c<8;c++){
    const float* pp = PAR + ((size_t)c*96+t)*26;
    #pragma unroll
    for(int e=0;e<24;e++) S[e] += pp[e];
    qss += pp[24]; kss += pp[25];
  }
  float qi = 1.0f/fmaxf(sqrtf(qss),1e-12f);
  kinv_s[t] = 1.0f/fmaxf(sqrtf(kss),1e-12f);
  __syncthreads();
  float tv = LD(t2,h);
  float v[24]; float m = NEGINF;
  #pragma unroll
  for(int e=0;e<24;e++){
    v[e] = S[e]*qi*kinv_s[h*24+e]*tv;
    m = fmaxf(m, v[e]);
  }
  float s=0.f;
  #pragma unroll
  for(int e=0;e<24;e++){ v[e]=__expf(v[e]-m); s+=v[e]; }
  float inv=1.0f/s;
  #pragma unroll
  for(int e=0;e<24;e++) ACA[t*24+e] = v[e]*inv;
}

// ---------------- K8d: x_ca[c][n] = sum_e A[h,d,e]*v_ca[h,n,e] (LDS-staged A) -------
__global__ void k_caout2(const float* __restrict__ ACA, const float* __restrict__ VCA,
                         float* __restrict__ XCA){
  __shared__ float A[2304];
  int t = threadIdx.x;
  for(int f=t; f<2304; f+=256) A[f] = ACA[f];
  __syncthreads();
  int h = t>>6, l = t&63;
  int n = blockIdx.x*64 + l;
  float vr[24];
  const float* vp = VCA + ((size_t)h*NN+n)*24;
  #pragma unroll
  for(int e=0;e<24;e+=4){
    float4 v = *reinterpret_cast<const float4*>(vp+e);
    vr[e]=v.x; vr[e+1]=v.y; vr[e+2]=v.z; vr[e+3]=v.w;
  }
  #pragma unroll
  for(int d=0;d<24;d++){
    float a=0.f;
    const float* ar = A + (h*24+d)*24;   // wave-uniform -> broadcast
    #pragma unroll
    for(int e=0;e<24;e++) a += ar[e]*vr[e];
    XCA[(h*24+d)*NN + n] = a;
  }
}

// ---------------- K9: epa proj + ax = xt + gamma*epa -> SKIPF f32[n][96] + SKIPH bf16[n][96] ----------------
__global__ void k_epa(const float* __restrict__ XSA, const float* __restrict__ XCA,
                      const void* __restrict__ x, const void* __restrict__ gamma,
                      const void* __restrict__ o1w, const void* __restrict__ o1b,
                      const void* __restrict__ o2w, const void* __restrict__ o2b,
                      float* __restrict__ SKIPF, ushort_t* __restrict__ SKIPH){
  int n = blockIdx.x*256 + threadIdx.x;
  int c0 = blockIdx.y*16;
  bool first = (c0 < 48);
  const float* src = first? XSA : XCA;
  const float* wp = (const float*)(first? o1w : o2w);
  const void* bb = first? o1b : o2b;
  int cb = first? c0 : c0-48;
  float acc[16];
  #pragma unroll
  for(int j=0;j<16;j++) acc[j]=0.f;
  for(int c=0;c<96;c+=4){
    float v0=src[(c+0)*NN+n], v1=src[(c+1)*NN+n], v2=src[(c+2)*NN+n], v3=src[(c+3)*NN+n];
    #pragma unroll
    for(int j=0;j<16;j++){
      const float4 wv = *reinterpret_cast<const float4*>(wp + (cb+j)*96 + c);
      acc[j] += wv.x*v0 + wv.y*v1 + wv.z*v2 + wv.w*v3;
    }
  }
  #pragma unroll
  for(int j=0;j<16;j++){
    int c = c0+j;
    float e = acc[j] + LD(bb, cb+j);
    float v = LD(x, c*NN+n) + 1.0f + LD(gamma,c)*e;
    SKIPF[n*96+c] = v;
    SKIPH[n*96+c] = f2b(v);
  }
}

// ---------------- prep: conv weights -> bf16 WB[t][tap][o][i] ----------------
__global__ void k_prep(const void* w0, const void* w1, const void* w2, const void* w3,
                       ushort_t* __restrict__ WB){
  int e = blockIdx.x*256 + threadIdx.x;
  if(e >= 4*WSZ) return;
  int t = e/WSZ, r = e%WSZ;
  int tap = r/9216, r2 = r%9216, o = r2/96, i = r2%96;
  const void* w = (t==0)? w0 : (t==1)? w1 : (t==2)? w2 : w3;
  WB[e] = f2b(LD(w, (o*96+i)*27 + tap));
}

// ---------------- prep: BN scale/shift per conv: BNS[t*192 + {o, 96+o}] ----------------
__global__ void k_bnprep(const void* b0, const void* b1, const void* b2, const void* b3,
                         float* __restrict__ BNS){
  int id = threadIdx.x;
  if(id >= 384) return;
  int t = id/96, o = id%96;
  const void* bn = (t==0)? b0 : (t==1)? b1 : (t==2)? b2 : b3;
  float g=LD(bn,o), b=LD(bn,96+o), mu=LD(bn,192+o), var=LD(bn,288+o);
  float s = g*rsqrtf(var+1e-5f);
  BNS[t*192+o] = s;
  BNS[t*192+96+o] = b - mu*s;
}

// ---------------- K10: MFMA implicit-GEMM conv3x3x3 + BN + res + lrelu ----------------
__global__ __launch_bounds__(256,2) void k_convm(
    const ushort_t* __restrict__ IN,   // bf16 [n][96]
    const ushort_t* __restrict__ WB,   // bf16 [27][96][96] (o-major, i contiguous)
    const float* __restrict__ BNS,     // [192] scale|shift
    const float* __restrict__ resf,    // f32 [n][96] or null
    ushort_t* __restrict__ outh,       // bf16 [n][96]
    float* __restrict__ outf)          // f32 [n][96] or null
{
  __shared__ float red[4][48][68];   // 52.2 KB -> 2 blocks/CU
  int tid = threadIdx.x;
  int w = tid>>6, lane = tid&63;
  int lan = lane&15, grp = lane>>4;
  int n0 = blockIdx.x*64;

  int nj[4], Xj[4], Yj[4], Zj[4];
  #pragma unroll
  for(int j=0;j<4;j++){
    int n = n0 + j*16 + lan;
    nj[j]=n; Xj[j]=n/640; int rr=n%640; Yj[j]=rr/16; Zj[j]=rr&15;
  }

  f32x4 acc[6][4];
  #pragma unroll
  for(int mt=0;mt<6;mt++)
    #pragma unroll
    for(int j=0;j<4;j++) acc[mt][j] = (f32x4)(0.f);

  int lo = (w*27)>>2, hi = ((w+1)*27)>>2;   // 6,7,7,7 taps
  for(int tap=lo; tap<hi; ++tap){
    int dx=tap/9-1, dy=(tap%9)/3-1, dz=tap%3-1;
    int off = dx*640 + dy*16 + dz;
    const ushort_t* wt = WB + tap*9216;
    const ushort_t* sp[4]; bool ok[4];
    #pragma unroll
    for(int j=0;j<4;j++){
      ok[j] = (unsigned)(Xj[j]+dx)<40u && (unsigned)(Yj[j]+dy)<40u && (unsigned)(Zj[j]+dz)<16u;
      sp[j] = IN + (nj[j]+off)*96 + grp*8;
    }
    #pragma unroll
    for(int s=0;s<3;s++){
      s16x8 a[6];
      #pragma unroll
      for(int mt=0;mt<6;mt++)
        a[mt] = *reinterpret_cast<const s16x8*>(wt + (mt*16+lan)*96 + s*32 + grp*8);
      #pragma unroll
      for(int j=0;j<4;j++){
        s16x8 b = {};
        if(ok[j]) b = *reinterpret_cast<const s16x8*>(sp[j] + s*32);
        #pragma unroll
        for(int mt=0;mt<6;mt++)
          acc[mt][j] = __builtin_amdgcn_mfma_f32_16x16x32_bf16(a[mt], b, acc[mt][j], 0,0,0);
      }
    }
  }

  // cross-wave reduce (2 chunks of 48 o) + fused epilogue
  int n_loc = tid&63;
  int ob = (tid>>6)*12;
  int n = n0 + n_loc;
  #pragma unroll
  for(int chunk=0; chunk<2; ++chunk){
    if(chunk) __syncthreads();
    #pragma unroll
    for(int m=0;m<3;m++){
      int mt = chunk*3+m;
      #pragma unroll
      for(int j=0;j<4;j++)
        #pragma unroll
        for(int r=0;r<4;r++)
          red[w][m*16 + grp*4 + r][j*16 + lan] = acc[mt][j][r];
    }
    __syncthreads();
    #pragma unroll
    for(int q=0;q<12;q++){
      int o = ob+q;
      float v = red[0][o][n_loc]+red[1][o][n_loc]+red[2][o][n_loc]+red[3][o][n_loc];
      int og = chunk*48 + o;
      v = v*BNS[og] + BNS[96+og];
      if(resf) v += resf[n*96+og];
      v = (v>=0.f)? v : 0.01f*v;
      if(outf) outf[n*96+og] = v;
      outh[n*96+og] = f2b(v);
    }
  }
}

// ---------------- K11: MFMA final: out[c][n] = skipf[n][c] + conv8(T3h)[c][n] + b8[c] ----------------
__global__ __launch_bounds__(256,2) void k_finm(
    const float* __restrict__ SKIPF, const ushort_t* __restrict__ T3H,
    const ushort_t* __restrict__ W8H, const void* __restrict__ b,
    float* __restrict__ out){
  int tid=threadIdx.x, w=tid>>6, lane=tid&63, lan=lane&15, grp=lane>>4;
  int n = blockIdx.x*64 + w*16 + lan;
  const ushort_t* bp = T3H + n*96;
  f32x4 acc[6];
  #pragma unroll
  for(int mt=0;mt<6;mt++) acc[mt] = (f32x4)(0.f);
  #pragma unroll
  for(int s=0;s<3;s++){
    s16x8 bb = *reinterpret_cast<const s16x8*>(bp + s*32 + grp*8);
    #pragma unroll
    for(int mt=0;mt<6;mt++){
      s16x8 a = *reinterpret_cast<const s16x8*>(W8H + (mt*16+lan)*96 + s*32 + grp*8);
      acc[mt] = __builtin_amdgcn_mfma_f32_16x16x32_bf16(a, bb, acc[mt], 0,0,0);
    }
  }
  #pragma unroll
  for(int mt=0;mt<6;mt++){
    #pragma unroll
    for(int r=0;r<4;r++){
      int o = mt*16 + grp*4 + r;
      out[o*NN+n] = SKIPF[n*96+o] + acc[mt][r] + LD(b,o);
    }
  }
}

extern "C" void kernel_launch(void* const* d_in, const int* in_sizes, int n_in,
                              void* d_out, int out_size, void* d_ws, size_t ws_size,
                              hipStream_t stream){
  const void* x     = d_in[0];
  const int*  rpi   = (const int*)d_in[1];
  const void* rct   = d_in[2];
  const void* sls   = d_in[3];
  const void* nw    = d_in[4];
  const void* nb    = d_in[5];
  const void* gamma = d_in[6];
  const void* wqkvv = d_in[7];
  const void* temp  = d_in[8];
  const void* temp2 = d_in[9];
  const void* qe    = d_in[10];
  const void* rbl   = d_in[11];
  const void* ltok  = d_in[12];
  const void* lbias = d_in[13];
  const void* srw   = d_in[14];
  const void* srb   = d_in[15];
  const void* epaw  = d_in[16];
  const void* epab  = d_in[17];
  const void* wkv   = d_in[18];
  const void* c1w   = d_in[19];
  const void* c1b   = d_in[20];
  const void* c2w   = d_in[21];
  const void* c2b   = d_in[22];
  const void* o1w   = d_in[23];
  const void* o1b   = d_in[24];
  const void* o2w   = d_in[25];
  const void* o2b   = d_in[26];
  const void* w51a  = d_in[27];
  const void* bn51a = d_in[28];
  const void* w51b  = d_in[29];
  const void* bn51b = d_in[30];
  const void* w52a  = d_in[31];
  const void* bn52a = d_in[32];
  const void* w52b  = d_in[33];
  const void* bn52b = d_in[34];
  const void* w8    = d_in[35];
  const void* b8    = d_in[36];

  float* ws = (float*)d_ws;
  const size_t S = SSLOT;
  ushort_t* XNH = (ushort_t*)ws; // slot 0 first half; dead after k_srm -> SKIPF
  float* SKIPF = ws;             // written by k_epa (after XNH dead)
  float* Q     = ws + 1*S;    // dead after k_cascore2 -> T1-ish (unused after)
  float* Kb    = ws + 2*S;    // dead after k_cascore2 -> T2F
  float* T2F   = ws + 2*S;
  float* VCA   = ws + 3*S;    // dead after k_caout2
  float* VSA   = ws + 4*S;    // dead after k_attn2 -> SKIPH/T1H (bf16)
  float* QN    = ws + 5*S;    // dead after k_attn2 -> T2H/T3H (bf16)
  float* QS    = ws + 6*S;    // dead after k_attn2
  float* XP2   = ws + 7*S;    // dead after k_pool -> XSA
  float* XSA   = ws + 7*S;
  float* XCA   = ws + 8*S;
  int*   rpiT  = (int*)(ws + 8*S);   // used only by k_attn2; overwritten by XCA later
  ushort_t* SKIPH = (ushort_t*)(ws + 4*S);
  ushort_t* T1H   = SKIPH + SSLOT;          // second half of slot 4
  ushort_t* T2H   = (ushort_t*)(ws + 5*S);
  ushort_t* T3H   = T2H + SSLOT;            // second half of slot 5
  float* SM  = ws + 9*S;
  float* pooled = SM;          // 4800
  float* KP     = SM + 4800;   // 4800
  float* VP     = SM + 9600;   // 4800
  float* KPN    = SM + 14400;  // 4800
  float* TAB    = SM + 19200;  // 16384
  float* ACA    = SM + 38080;  // 2304
  ushort_t* WB  = (ushort_t*)(SM + 40960);  // 4*248832 bf16 (497664 floats)
  float* BNS    = SM + 40960 + 497664;      // 768 floats
  ushort_t* WQH = (ushort_t*)(BNS + 768);   // 36864 bf16 (18432 f)
  ushort_t* WSH = WQH + 36864;              // 9216 bf16 (4608 f)
  ushort_t* W8H = WSH + 9216;               // 9216 bf16 (4608 f)
  float* PAR    = BNS + 768 + 18432 + 4608 + 4608;  // 8*96*26 floats

  k_prep  <<<3888,  256, 0, stream>>>(w51a, w51b, w52a, w52b, WB);
  k_bnprep<<<1,     384, 0, stream>>>(bn51a, bn51b, bn52a, bn52b, BNS);
  k_prepw <<<144,   256, 0, stream>>>(wqkvv, srw, w8, WQH, WSH, W8H);
  k_rpit  <<<5000,  256, 0, stream>>>(rpi, rpiT);
  k_ln    <<<100,   256, 0, stream>>>(x, nw, nb, XNH);
  k_qkvvm <<<dim3(400,2), 256, 0, stream>>>(XNH, WQH, Q);
  k_qs    <<<400,   256, 0, stream>>>(Q, temp, sls, qe, QN, QS);
  k_srm   <<<400,   256, 0, stream>>>(XNH, WSH, srb, XP2);
  k_pool  <<<4800,  64,  0, stream>>>(XP2, pooled);
  k_lnkv  <<<50,    256, 0, stream>>>(pooled, epaw, epab, wkv, KP, VP);
  k_kpn   <<<1,     256, 0, stream>>>(KP, KPN);
  k_tab   <<<4096,  512, 0, stream>>>(rct, c1w, c1b, c2w, c2b, TAB);
  k_attn2 <<<dim3(400,4), 64, 0, stream>>>(QS, QN, Kb, VSA, KPN, VP, TAB, rpiT,
                                           rbl, ltok, lbias, XSA);
  k_cascore2<<<dim3(96,8), 256, 0, stream>>>(Q, Kb, PAR);
  k_casm2 <<<1,     96,  0, stream>>>(PAR, temp2, ACA);
  k_caout2<<<400,   256, 0, stream>>>(ACA, VCA, XCA);
  k_epa   <<<dim3(100,6),  256, 0, stream>>>(XSA, XCA, x, gamma, o1w, o1b, o2w, o2b,
                                             SKIPF, SKIPH);
  // resblock 1
  k_convm <<<400, 256, 0, stream>>>(SKIPH, WB,        BNS,     nullptr, T1H, nullptr);
  k_convm <<<400, 256, 0, stream>>>(T1H,   WB+WSZ,    BNS+192, SKIPF,   T2H, T2F);
  // resblock 2
  k_convm <<<400, 256, 0, stream>>>(T2H,   WB+2*WSZ,  BNS+384, nullptr, T1H, nullptr);
  k_convm <<<400, 256, 0, stream>>>(T1H,   WB+3*WSZ,  BNS+576, T2F,     T3H, nullptr);
  k_finm  <<<400, 256, 0, stream>>>(SKIPF, T3H, W8H, b8, (float*)d_out);
}

// Round 6
// 516.553 us; speedup vs baseline: 4.3536x; 1.1672x over previous
//
#include <hip/hip_runtime.h>
#include <hip/hip_bf16.h>

// Problem constants
#define NN 25600      // D*H*W = 16*40*40 ; attn grid n = d0*1600 + h0*40 + w0
#define CC 96
#define NHh 4
#define HDd 24
#define SSLOT 2457600 // NN*CC floats per workspace slot
#define WSZ 248832    // 27*96*96 elems per conv weight tensor

typedef unsigned short ushort_t;
typedef float f32x4 __attribute__((ext_vector_type(4)));
typedef short s16x8 __attribute__((ext_vector_type(8)));

// All tensors are float32 on device (per reference dtypes).
__device__ __forceinline__ float LD(const void* p, int i){
  return ((const float*)p)[i];
}
__device__ __forceinline__ float b2f(ushort_t u){ return __uint_as_float(((unsigned)u)<<16); }
__device__ __forceinline__ ushort_t f2b(float f){   // RNE bf16 round
  unsigned u = __float_as_uint(f);
  unsigned r = (u + 0x7fffu + ((u>>16)&1u))>>16;
  return (ushort_t)r;
}

#define NEGINF (-3.0e38f)

// ---------------- K1: xt = x+1, LayerNorm over C -> XNH bf16 [n][96] ----------------
__global__ void k_ln(const void* __restrict__ x, const void* __restrict__ nw,
                     const void* __restrict__ nb, ushort_t* __restrict__ XNH){
  int n = blockIdx.x*256 + threadIdx.x;
  float s=0.f, ss=0.f;
  for(int c=0;c<CC;c++){ float v = LD(x, c*NN+n)+1.0f; s+=v; ss+=v*v; }
  float mu = s*(1.0f/CC);
  float var = ss*(1.0f/CC) - mu*mu;
  float inv = rsqrtf(var + 1e-5f);
  for(int c=0;c<CC;c++){
    float v = LD(x, c*NN+n)+1.0f;
    XNH[n*96+c] = f2b((v-mu)*inv*LD(nw,c) + LD(nb,c));
  }
}

// ---------------- prep: wqkvv/srw/w8 f32 -> bf16 (row-major [o][c]) ----------------
__global__ void k_prepw(const void* wq, const void* wsr, const void* w8,
                        ushort_t* __restrict__ WQH, ushort_t* __restrict__ WSH,
                        ushort_t* __restrict__ W8H){
  int e = blockIdx.x*256 + threadIdx.x;
  if(e < 36864) WQH[e] = f2b(LD(wq,e));
  if(e < 9216){ WSH[e] = f2b(LD(wsr,e)); W8H[e] = f2b(LD(w8,e)); }
}

// ---------------- prep: rpi [n][50] -> rpiT [50][n] (coalesced gather in attn) -------
__global__ void k_rpit(const int* __restrict__ rpi, int* __restrict__ rpiT){
  int e = blockIdx.x*256 + threadIdx.x;
  if(e >= 50*NN) return;
  int p = e/NN, n = e%NN;
  rpiT[e] = rpi[n*50+p];
}

// ---------------- K2: qkvv MFMA GEMM -> Q/K/VCA/VSA f32 [h][n][d] ----------------
__global__ __launch_bounds__(256,2) void k_qkvvm(
    const ushort_t* __restrict__ XNH, const ushort_t* __restrict__ WQH,
    float* __restrict__ out){ // out = Q base; slots s*SSLOT
  int tid=threadIdx.x, w=tid>>6, lane=tid&63, lan=lane&15, grp=lane>>4;
  int n = blockIdx.x*64 + w*16 + lan;
  int ybase = blockIdx.y*192;
  const ushort_t* bp = XNH + n*96;
  f32x4 acc[12];
  #pragma unroll
  for(int mt=0;mt<12;mt++) acc[mt] = (f32x4)(0.f);
  #pragma unroll
  for(int s=0;s<3;s++){
    s16x8 b = *reinterpret_cast<const s16x8*>(bp + s*32 + grp*8);
    #pragma unroll
    for(int mt=0;mt<12;mt++){
      s16x8 a = *reinterpret_cast<const s16x8*>(WQH + (ybase+mt*16+lan)*96 + s*32 + grp*8);
      acc[mt] = __builtin_amdgcn_mfma_f32_16x16x32_bf16(a, b, acc[mt], 0,0,0);
    }
  }
  #pragma unroll
  for(int mt=0;mt<12;mt++){
    #pragma unroll
    for(int r=0;r<4;r++){
      int o = ybase + mt*16 + grp*4 + r;
      int sl = o/96, rr = o%96, h = rr/24, dd = rr%24;
      out[sl*SSLOT + (h*NN+n)*24 + dd] = acc[mt][r];
    }
  }
}

// ---------------- K4: sr MFMA GEMM + gelu -> XP2 f32 [c][n] ----------------
__global__ __launch_bounds__(256,2) void k_srm(
    const ushort_t* __restrict__ XNH, const ushort_t* __restrict__ WSH,
    const void* __restrict__ bias, float* __restrict__ XP2){
  int tid=threadIdx.x, w=tid>>6, lane=tid&63, lan=lane&15, grp=lane>>4;
  int n = blockIdx.x*64 + w*16 + lan;
  const ushort_t* bp = XNH + n*96;
  f32x4 acc[6];
  #pragma unroll
  for(int mt=0;mt<6;mt++) acc[mt] = (f32x4)(0.f);
  #pragma unroll
  for(int s=0;s<3;s++){
    s16x8 b = *reinterpret_cast<const s16x8*>(bp + s*32 + grp*8);
    #pragma unroll
    for(int mt=0;mt<6;mt++){
      s16x8 a = *reinterpret_cast<const s16x8*>(WSH + (mt*16+lan)*96 + s*32 + grp*8);
      acc[mt] = __builtin_amdgcn_mfma_f32_16x16x32_bf16(a, b, acc[mt], 0,0,0);
    }
  }
  #pragma unroll
  for(int mt=0;mt<6;mt++){
    #pragma unroll
    for(int r=0;r<4;r++){
      int o = mt*16 + grp*4 + r;
      float y = acc[mt][r] + LD(bias,o);
      y = 0.5f*y*(1.0f + erff(y*0.70710678118f));
      XP2[o*NN+n] = y;
    }
  }
}

// ---------------- K3: qn = l2(q), qs = (qn+qe)*softplus(T)*sls ----------------
__global__ void k_qs(const float* __restrict__ Q, const void* __restrict__ temp,
                     const void* __restrict__ sls, const void* __restrict__ qe,
                     float* __restrict__ QN, float* __restrict__ QS){
  int id = blockIdx.x*256 + threadIdx.x;
  if(id >= NHh*NN) return;
  int h = id/NN, n = id%NN;
  const float* qr = Q + (h*NN+n)*24;
  float qv[24]; float ss=0.f;
  #pragma unroll
  for(int d=0;d<24;d++){ qv[d]=qr[d]; ss+=qv[d]*qv[d]; }
  float inv = 1.0f/fmaxf(sqrtf(ss), 1e-12f);
  float t = LD(temp,h);
  float sp = log1pf(expf(t)) * LD(sls,0);
  #pragma unroll
  for(int d=0;d<24;d++){
    float qn = qv[d]*inv;
    QN[(h*NN+n)*24+d] = qn;
    QS[(h*NN+n)*24+d] = (qn + LD(qe, h*24+d))*sp;
  }
}

// ---------------- K5: 8x8x8 average pool over (X,Y,Z)=(40,40,16) view ----------------
__global__ void k_pool(const float* __restrict__ XP2, float* __restrict__ pooled){
  int bb = blockIdx.x;
  int c = bb % CC, p = bb / CC;
  int ph = p/10, pw = (p%10)/2, pd = p%2;
  float s = 0.f;
  for(int t=threadIdx.x; t<512; t+=64){
    int i=t>>6, j=(t>>3)&7, k=t&7;
    int m = (ph*8+i)*640 + (pw*8+j)*16 + (pd*8+k);
    s += XP2[c*NN+m];
  }
  #pragma unroll
  for(int off=32;off;off>>=1) s += __shfl_down(s, off);
  if(threadIdx.x==0) pooled[p*CC+c] = s*(1.0f/512.0f);
}

// ---------------- K5b: LN(pooled) then kv = xp @ w_kv^T -> KP/VP [h][p][d] ----------------
__global__ void k_lnkv(const float* __restrict__ pooled, const void* __restrict__ ew,
                       const void* __restrict__ eb, const void* __restrict__ wkv,
                       float* __restrict__ KP, float* __restrict__ VP){
  __shared__ float row[96], lnr[96], st[2];
  int p = blockIdx.x, t = threadIdx.x;
  if(t<96) row[t] = pooled[p*96+t];
  __syncthreads();
  if(t==0){
    float s=0.f, ss=0.f;
    for(int c=0;c<96;c++){ float v=row[c]; s+=v; ss+=v*v; }
    float mu=s*(1.0f/96.0f);
    float var=ss*(1.0f/96.0f)-mu*mu;
    st[0]=mu; st[1]=rsqrtf(var+1e-5f);
  }
  __syncthreads();
  if(t<96) lnr[t] = (row[t]-st[0])*st[1]*LD(ew,t) + LD(eb,t);
  __syncthreads();
  if(t<192){
    float a=0.f;
    for(int c=0;c<96;c++) a += LD(wkv, t*96+c)*lnr[c];
    int g=t/24, d=t%24;
    if(g<4) KP[(g*50+p)*24+d]=a;
    else    VP[((g-4)*50+p)*24+d]=a;
  }
}

// ---------------- K5c: k_pool l2-normalize over d ----------------
__global__ void k_kpn(const float* __restrict__ KP, float* __restrict__ KPN){
  int t = threadIdx.x;
  if(t>=200) return;
  const float* r = KP + t*24;
  float ss=0.f;
  #pragma unroll
  for(int d=0;d<24;d++) ss += r[d]*r[d];
  float inv = 1.0f/fmaxf(sqrtf(ss),1e-12f);
  #pragma unroll
  for(int d=0;d<24;d++) KPN[t*24+d] = r[d]*inv;
}

// ---------------- K6: cpb MLP -> tab[T][NH] ----------------
__global__ void k_tab(const void* __restrict__ rct, const void* __restrict__ w1,
                      const void* __restrict__ b1, const void* __restrict__ w2,
                      const void* __restrict__ b2, float* __restrict__ TAB){
  __shared__ float red[32];
  int tt = blockIdx.x, j = threadIdx.x;
  float r0=LD(rct,tt*3), r1=LD(rct,tt*3+1), r2=LD(rct,tt*3+2);
  float hj = r0*LD(w1,j*3) + r1*LD(w1,j*3+1) + r2*LD(w1,j*3+2) + LD(b1,j);
  hj = fmaxf(hj, 0.f);
  int lane=j&63, wid=j>>6;
  for(int h=0;h<4;h++){
    float v = hj*LD(w2, h*512+j);
    #pragma unroll
    for(int off=32;off;off>>=1) v += __shfl_down(v, off);
    if(lane==0) red[wid*4+h]=v;
  }
  __syncthreads();
  if(j<4){
    float s=0.f;
    for(int w=0;w<8;w++) s += red[w*4+j];
    TAB[tt*4+j] = s + LD(b2,j);
  }
}

// ---------------- K7: LDS-tiled local+pool attention, 4 waves / 4 d0-planes ----------
// Block = 256 threads; wave w owns plane d0 = g*4+w, 8x8 (h0,w0) queries.
// K halo = 6x10x10 = 600 rows x f32[24] pad 25 = 60 KB LDS; V restaged after scores.
__global__ __launch_bounds__(256) void k_attn3(
    const float* __restrict__ QS, const float* __restrict__ QN,
    const float* __restrict__ K,  const float* __restrict__ VSA,
    const float* __restrict__ KPN,const float* __restrict__ VP,
    const float* __restrict__ TAB,const int* __restrict__ rpiT,
    const void* __restrict__ rbl, const void* __restrict__ ltok,
    const void* __restrict__ lbias, float* __restrict__ XSA)
{
  __shared__ float KV[600*25];   // 60 KB -> 2 blocks/CU
  int tile = blockIdx.x, h = blockIdx.y;
  int g = tile/25, sp = tile%25, hg = sp/5, wg = sp%5;
  int tid = threadIdx.x, w = tid>>6, lane = tid&63;
  int hy = lane>>3, wx = lane&7;
  int d0 = g*4 + w;
  int h0 = hg*8+hy, w0 = wg*8+wx;
  int n = d0*1600 + h0*40 + w0;

  // ---- stage K halo: 600 rows x 6 float4, all 256 threads ----
  const float* Kh = K + (size_t)h*NN*24;
  for(int f=tid; f<3600; f+=256){
    int row = f/6, q = f%6;
    int dr = row/100, yr = (row%100)/10, xr = row%10;
    int zc = min(max(g*4+dr-1,0),15), yc = min(max(hg*8+yr-1,0),39), xc = min(max(wg*8+xr-1,0),39);
    float4 v = *reinterpret_cast<const float4*>(Kh + (zc*1600+yc*40+xc)*24 + q*4);
    *reinterpret_cast<float4*>(KV + row*25 + q*4) = v;
  }

  // ---- lt[k] = lbias + qn . ltok (ltok loads wave-uniform) ----
  float lt[27];
  {
    float qn[24];
    const float* qnp = QN + ((size_t)h*NN+n)*24;
    #pragma unroll
    for(int d=0; d<24; d+=4){
      float4 a = *reinterpret_cast<const float4*>(qnp+d);
      qn[d]=a.x; qn[d+1]=a.y; qn[d+2]=a.z; qn[d+3]=a.w;
    }
    #pragma unroll
    for(int k=0;k<27;k++) lt[k] = LD(lbias, h*27+k);
    #pragma unroll
    for(int d=0; d<24; d++){
      float q = qn[d];
      #pragma unroll
      for(int k=0;k<27;k++) lt[k] += q*LD(ltok, (h*24+d)*27+k);
    }
  }

  float qs[24];
  const float* qsp = QS + ((size_t)h*NN+n)*24;
  #pragma unroll
  for(int d=0; d<24; d+=4){
    float4 a = *reinterpret_cast<const float4*>(qsp+d);
    qs[d]=a.x; qs[d+1]=a.y; qs[d+2]=a.z; qs[d+3]=a.w;
  }

  __syncthreads();

  // ---- scores: 27 local (LDS plane w+kz) + 50 pool (uniform KPN) ----
  float av[77];
  #pragma unroll
  for(int k=0;k<27;k++){
    int kz=k/9, ky=(k%9)/3, kx=k%3;
    bool ok = (unsigned)(d0+kz-1)<16u && (unsigned)(h0+ky-1)<40u && (unsigned)(w0+kx-1)<40u;
    float sc = NEGINF;
    if(ok){
      const float* kr = KV + ((w+kz)*100 + (hy+ky)*10 + (wx+kx))*25;
      sc = LD(rbl, h*27+k);
      #pragma unroll
      for(int d=0;d<24;d+=4){
        float4 kv = *reinterpret_cast<const float4*>(kr+d);
        sc += qs[d]*kv.x + qs[d+1]*kv.y + qs[d+2]*kv.z + qs[d+3]*kv.w;
      }
    }
    av[k]=sc;
  }
  #pragma unroll
  for(int p=0;p<50;p++){
    const float* kr = KPN + ((size_t)h*50+p)*24;
    float sc = TAB[rpiT[(size_t)p*NN+n]*4 + h];
    #pragma unroll
    for(int d=0;d<24;d+=4){
      float4 kv = *reinterpret_cast<const float4*>(kr+d);
      sc += qs[d]*kv.x + qs[d+1]*kv.y + qs[d+2]*kv.z + qs[d+3]*kv.w;
    }
    av[27+p]=sc;
  }

  // ---- softmax over 77 (registers) ----
  float m = av[0];
  #pragma unroll
  for(int k=1;k<77;k++) m = fmaxf(m, av[k]);
  float s = 0.f;
  #pragma unroll
  for(int k=0;k<77;k++){ av[k] = __expf(av[k]-m); s += av[k]; }
  float inv = 1.0f/s;

  // ---- restage V over K ----
  __syncthreads();
  const float* Vh = VSA + (size_t)h*NN*24;
  for(int f=tid; f<3600; f+=256){
    int row = f/6, q = f%6;
    int dr = row/100, yr = (row%100)/10, xr = row%10;
    int zc = min(max(g*4+dr-1,0),15), yc = min(max(hg*8+yr-1,0),39), xc = min(max(wg*8+xr-1,0),39);
    float4 v = *reinterpret_cast<const float4*>(Vh + (zc*1600+yc*40+xc)*24 + q*4);
    *reinterpret_cast<float4*>(KV + row*25 + q*4) = v;
  }
  __syncthreads();

  // ---- PV accumulate ----
  float acc[24];
  #pragma unroll
  for(int d=0;d<24;d++) acc[d]=0.f;
  #pragma unroll
  for(int k=0;k<27;k++){
    int kz=k/9, ky=(k%9)/3, kx=k%3;
    bool ok = (unsigned)(d0+kz-1)<16u && (unsigned)(h0+ky-1)<40u && (unsigned)(w0+kx-1)<40u;
    if(ok){
      float wgt = av[k]*inv + lt[k];
      const float* vr = KV + ((w+kz)*100 + (hy+ky)*10 + (wx+kx))*25;
      #pragma unroll
      for(int d=0;d<24;d+=4){
        float4 vv = *reinterpret_cast<const float4*>(vr+d);
        acc[d] += wgt*vv.x; acc[d+1] += wgt*vv.y; acc[d+2] += wgt*vv.z; acc[d+3] += wgt*vv.w;
      }
    }
  }
  #pragma unroll
  for(int p=0;p<50;p++){
    float wgt = av[27+p]*inv;
    const float* vr = VP + ((size_t)h*50+p)*24;
    #pragma unroll
    for(int d=0;d<24;d+=4){
      float4 vv = *reinterpret_cast<const float4*>(vr+d);
      acc[d] += wgt*vv.x; acc[d+1] += wgt*vv.y; acc[d+2] += wgt*vv.z; acc[d+3] += wgt*vv.w;
    }
  }
  #pragma unroll
  for(int d=0;d<24;d++)
    XSA[((size_t)h*24+d)*NN + n] = acc[d];
}

// ---------------- K8a+b: cross-attn scores + norms, split-K over n (8 chunks) -------
__global__ void k_cascore2(const float* __restrict__ Q, const float* __restrict__ K,
                           float* __restrict__ PAR){
  __shared__ float red[4][26];
  int hd = blockIdx.x, h = hd/24, d = hd%24;
  int n0 = blockIdx.y*3200;
  float acc[24]; float qss=0.f, kss=0.f;
  #pragma unroll
  for(int e=0;e<24;e++) acc[e]=0.f;
  for(int i=threadIdx.x; i<3200; i+=256){
    int n = n0 + i;
    const float* kr = K + ((size_t)h*NN+n)*24;
    float qv = Q[((size_t)h*NN+n)*24+d];
    qss += qv*qv;
    float kd = kr[d]; kss += kd*kd;
    #pragma unroll
    for(int e=0;e<24;e++) acc[e] += qv*kr[e];
  }
  int lane=threadIdx.x&63, wid=threadIdx.x>>6;
  #pragma unroll
  for(int j=0;j<26;j++){
    float v = (j<24)? acc[j] : (j==24? qss : kss);
    #pragma unroll
    for(int off=32;off;off>>=1) v += __shfl_down(v, off);
    if(lane==0) red[wid][j]=v;
  }
  __syncthreads();
  if(threadIdx.x<26){
    int j=threadIdx.x;
    PAR[((size_t)blockIdx.y*96+hd)*26 + j] = red[0][j]+red[1][j]+red[2][j]+red[3][j];
  }
}

// ---------------- K8c: reduce partials, softmax -> ACA ----------------
__global__ void k_casm2(const float* __restrict__ PAR, const void* __restrict__ t2,
                        float* __restrict__ ACA){
  __shared__ float kinv_s[96];
  int t = threadIdx.x;  // blockDim = 96
  int h = t/24;
  float S[24]; float qss=0.f, kss=0.f;
  #pragma unroll
  for(int e=0;e<24;e++) S[e]=0.f;
  for(int c=0;c<8;c++){
    const float* pp = PAR + ((size_t)c*96+t)*26;
    #pragma unroll
    for(int e=0;e<24;e++) S[e] += pp[e];
    qss += pp[24]; kss += pp[25];
  }
  float qi = 1.0f/fmaxf(sqrtf(qss),1e-12f);
  kinv_s[t] = 1.0f/fmaxf(sqrtf(kss),1e-12f);
  __syncthreads();
  float tv = LD(t2,h);
  float v[24]; float m = NEGINF;
  #pragma unroll
  for(int e=0;e<24;e++){
    v[e] = S[e]*qi*kinv_s[h*24+e]*tv;
    m = fmaxf(m, v[e]);
  }
  float s=0.f;
  #pragma unroll
  for(int e=0;e<24;e++){ v[e]=__expf(v[e]-m); s+=v[e]; }
  float inv=1.0f/s;
  #pragma unroll
  for(int e=0;e<24;e++) ACA[t*24+e] = v[e]*inv;
}

// ---------------- K8d: x_ca[c][n] = sum_e A[h,d,e]*v_ca[h,n,e] (LDS-staged A) -------
__global__ void k_caout2(const float* __restrict__ ACA, const float* __restrict__ VCA,
                         float* __restrict__ XCA){
  __shared__ float A[2304];
  int t = threadIdx.x;
  for(int f=t; f<2304; f+=256) A[f] = ACA[f];
  __syncthreads();
  int h = t>>6, l = t&63;
  int n = blockIdx.x*64 + l;
  float vr[24];
  const float* vp = VCA + ((size_t)h*NN+n)*24;
  #pragma unroll
  for(int e=0;e<24;e+=4){
    float4 v = *reinterpret_cast<const float4*>(vp+e);
    vr[e]=v.x; vr[e+1]=v.y; vr[e+2]=v.z; vr[e+3]=v.w;
  }
  #pragma unroll
  for(int d=0;d<24;d++){
    float a=0.f;
    const float* ar = A + (h*24+d)*24;   // wave-uniform -> broadcast
    #pragma unroll
    for(int e=0;e<24;e++) a += ar[e]*vr[e];
    XCA[(h*24+d)*NN + n] = a;
  }
}

// ---------------- K9: epa proj + ax = xt + gamma*epa -> SKIPF f32[n][96] + SKIPH bf16[n][96] ----------------
__global__ void k_epa(const float* __restrict__ XSA, const float* __restrict__ XCA,
                      const void* __restrict__ x, const void* __restrict__ gamma,
                      const void* __restrict__ o1w, const void* __restrict__ o1b,
                      const void* __restrict__ o2w, const void* __restrict__ o2b,
                      float* __restrict__ SKIPF, ushort_t* __restrict__ SKIPH){
  int n = blockIdx.x*256 + threadIdx.x;
  int c0 = blockIdx.y*16;
  bool first = (c0 < 48);
  const float* src = first? XSA : XCA;
  const float* wp = (const float*)(first? o1w : o2w);
  const void* bb = first? o1b : o2b;
  int cb = first? c0 : c0-48;
  float acc[16];
  #pragma unroll
  for(int j=0;j<16;j++) acc[j]=0.f;
  for(int c=0;c<96;c+=4){
    float v0=src[(c+0)*NN+n], v1=src[(c+1)*NN+n], v2=src[(c+2)*NN+n], v3=src[(c+3)*NN+n];
    #pragma unroll
    for(int j=0;j<16;j++){
      const float4 wv = *reinterpret_cast<const float4*>(wp + (cb+j)*96 + c);
      acc[j] += wv.x*v0 + wv.y*v1 + wv.z*v2 + wv.w*v3;
    }
  }
  #pragma unroll
  for(int j=0;j<16;j++){
    int c = c0+j;
    float e = acc[j] + LD(bb, cb+j);
    float v = LD(x, c*NN+n) + 1.0f + LD(gamma,c)*e;
    SKIPF[n*96+c] = v;
    SKIPH[n*96+c] = f2b(v);
  }
}

// ---------------- prep: conv weights -> bf16 WB[t][tap][o][i] ----------------
__global__ void k_prep(const void* w0, const void* w1, const void* w2, const void* w3,
                       ushort_t* __restrict__ WB){
  int e = blockIdx.x*256 + threadIdx.x;
  if(e >= 4*WSZ) return;
  int t = e/WSZ, r = e%WSZ;
  int tap = r/9216, r2 = r%9216, o = r2/96, i = r2%96;
  const void* w = (t==0)? w0 : (t==1)? w1 : (t==2)? w2 : w3;
  WB[e] = f2b(LD(w, (o*96+i)*27 + tap));
}

// ---------------- prep: BN scale/shift per conv: BNS[t*192 + {o, 96+o}] ----------------
__global__ void k_bnprep(const void* b0, const void* b1, const void* b2, const void* b3,
                         float* __restrict__ BNS){
  int id = threadIdx.x;
  if(id >= 384) return;
  int t = id/96, o = id%96;
  const void* bn = (t==0)? b0 : (t==1)? b1 : (t==2)? b2 : b3;
  float g=LD(bn,o), b=LD(bn,96+o), mu=LD(bn,192+o), var=LD(bn,288+o);
  float s = g*rsqrtf(var+1e-5f);
  BNS[t*192+o] = s;
  BNS[t*192+96+o] = b - mu*s;
}

// ---------------- K10: MFMA implicit-GEMM conv3x3x3 + BN + res + lrelu ----------------
__global__ __launch_bounds__(256,2) void k_convm(
    const ushort_t* __restrict__ IN,   // bf16 [n][96]
    const ushort_t* __restrict__ WB,   // bf16 [27][96][96] (o-major, i contiguous)
    const float* __restrict__ BNS,     // [192] scale|shift
    const float* __restrict__ resf,    // f32 [n][96] or null
    ushort_t* __restrict__ outh,       // bf16 [n][96]
    float* __restrict__ outf)          // f32 [n][96] or null
{
  __shared__ float red[4][48][68];   // 52.2 KB -> 2 blocks/CU
  int tid = threadIdx.x;
  int w = tid>>6, lane = tid&63;
  int lan = lane&15, grp = lane>>4;
  int n0 = blockIdx.x*64;

  int nj[4], Xj[4], Yj[4], Zj[4];
  #pragma unroll
  for(int j=0;j<4;j++){
    int n = n0 + j*16 + lan;
    nj[j]=n; Xj[j]=n/640; int rr=n%640; Yj[j]=rr/16; Zj[j]=rr&15;
  }

  f32x4 acc[6][4];
  #pragma unroll
  for(int mt=0;mt<6;mt++)
    #pragma unroll
    for(int j=0;j<4;j++) acc[mt][j] = (f32x4)(0.f);

  int lo = (w*27)>>2, hi = ((w+1)*27)>>2;   // 6,7,7,7 taps
  for(int tap=lo; tap<hi; ++tap){
    int dx=tap/9-1, dy=(tap%9)/3-1, dz=tap%3-1;
    int off = dx*640 + dy*16 + dz;
    const ushort_t* wt = WB + tap*9216;
    const ushort_t* sp[4]; bool ok[4];
    #pragma unroll
    for(int j=0;j<4;j++){
      ok[j] = (unsigned)(Xj[j]+dx)<40u && (unsigned)(Yj[j]+dy)<40u && (unsigned)(Zj[j]+dz)<16u;
      sp[j] = IN + (nj[j]+off)*96 + grp*8;
    }
    #pragma unroll
    for(int s=0;s<3;s++){
      s16x8 a[6];
      #pragma unroll
      for(int mt=0;mt<6;mt++)
        a[mt] = *reinterpret_cast<const s16x8*>(wt + (mt*16+lan)*96 + s*32 + grp*8);
      #pragma unroll
      for(int j=0;j<4;j++){
        s16x8 b = {};
        if(ok[j]) b = *reinterpret_cast<const s16x8*>(sp[j] + s*32);
        #pragma unroll
        for(int mt=0;mt<6;mt++)
          acc[mt][j] = __builtin_amdgcn_mfma_f32_16x16x32_bf16(a[mt], b, acc[mt][j], 0,0,0);
      }
    }
  }

  // cross-wave reduce (2 chunks of 48 o) + fused epilogue
  int n_loc = tid&63;
  int ob = (tid>>6)*12;
  int n = n0 + n_loc;
  #pragma unroll
  for(int chunk=0; chunk<2; ++chunk){
    if(chunk) __syncthreads();
    #pragma unroll
    for(int m=0;m<3;m++){
      int mt = chunk*3+m;
      #pragma unroll
      for(int j=0;j<4;j++)
        #pragma unroll
        for(int r=0;r<4;r++)
          red[w][m*16 + grp*4 + r][j*16 + lan] = acc[mt][j][r];
    }
    __syncthreads();
    #pragma unroll
    for(int q=0;q<12;q++){
      int o = ob+q;
      float v = red[0][o][n_loc]+red[1][o][n_loc]+red[2][o][n_loc]+red[3][o][n_loc];
      int og = chunk*48 + o;
      v = v*BNS[og] + BNS[96+og];
      if(resf) v += resf[n*96+og];
      v = (v>=0.f)? v : 0.01f*v;
      if(outf) outf[n*96+og] = v;
      outh[n*96+og] = f2b(v);
    }
  }
}

// ---------------- K11: MFMA final: out[c][n] = skipf[n][c] + conv8(T3h)[c][n] + b8[c] ----------------
__global__ __launch_bounds__(256,2) void k_finm(
    const float* __restrict__ SKIPF, const ushort_t* __restrict__ T3H,
    const ushort_t* __restrict__ W8H, const void* __restrict__ b,
    float* __restrict__ out){
  int tid=threadIdx.x, w=tid>>6, lane=tid&63, lan=lane&15, grp=lane>>4;
  int n = blockIdx.x*64 + w*16 + lan;
  const ushort_t* bp = T3H + n*96;
  f32x4 acc[6];
  #pragma unroll
  for(int mt=0;mt<6;mt++) acc[mt] = (f32x4)(0.f);
  #pragma unroll
  for(int s=0;s<3;s++){
    s16x8 bb = *reinterpret_cast<const s16x8*>(bp + s*32 + grp*8);
    #pragma unroll
    for(int mt=0;mt<6;mt++){
      s16x8 a = *reinterpret_cast<const s16x8*>(W8H + (mt*16+lan)*96 + s*32 + grp*8);
      acc[mt] = __builtin_amdgcn_mfma_f32_16x16x32_bf16(a, bb, acc[mt], 0,0,0);
    }
  }
  #pragma unroll
  for(int mt=0;mt<6;mt++){
    #pragma unroll
    for(int r=0;r<4;r++){
      int o = mt*16 + grp*4 + r;
      out[o*NN+n] = SKIPF[n*96+o] + acc[mt][r] + LD(b,o);
    }
  }
}

extern "C" void kernel_launch(void* const* d_in, const int* in_sizes, int n_in,
                              void* d_out, int out_size, void* d_ws, size_t ws_size,
                              hipStream_t stream){
  const void* x     = d_in[0];
  const int*  rpi   = (const int*)d_in[1];
  const void* rct   = d_in[2];
  const void* sls   = d_in[3];
  const void* nw    = d_in[4];
  const void* nb    = d_in[5];
  const void* gamma = d_in[6];
  const void* wqkvv = d_in[7];
  const void* temp  = d_in[8];
  const void* temp2 = d_in[9];
  const void* qe    = d_in[10];
  const void* rbl   = d_in[11];
  const void* ltok  = d_in[12];
  const void* lbias = d_in[13];
  const void* srw   = d_in[14];
  const void* srb   = d_in[15];
  const void* epaw  = d_in[16];
  const void* epab  = d_in[17];
  const void* wkv   = d_in[18];
  const void* c1w   = d_in[19];
  const void* c1b   = d_in[20];
  const void* c2w   = d_in[21];
  const void* c2b   = d_in[22];
  const void* o1w   = d_in[23];
  const void* o1b   = d_in[24];
  const void* o2w   = d_in[25];
  const void* o2b   = d_in[26];
  const void* w51a  = d_in[27];
  const void* bn51a = d_in[28];
  const void* w51b  = d_in[29];
  const void* bn51b = d_in[30];
  const void* w52a  = d_in[31];
  const void* bn52a = d_in[32];
  const void* w52b  = d_in[33];
  const void* bn52b = d_in[34];
  const void* w8    = d_in[35];
  const void* b8    = d_in[36];

  float* ws = (float*)d_ws;
  const size_t S = SSLOT;
  ushort_t* XNH = (ushort_t*)ws; // slot 0 first half; dead after k_srm -> SKIPF
  float* SKIPF = ws;             // written by k_epa (after XNH dead)
  float* Q     = ws + 1*S;    // dead after k_cascore2
  float* Kb    = ws + 2*S;    // dead after k_cascore2 -> T2F
  float* T2F   = ws + 2*S;
  float* VCA   = ws + 3*S;    // dead after k_caout2
  float* VSA   = ws + 4*S;    // dead after k_attn3 -> SKIPH/T1H (bf16)
  float* QN    = ws + 5*S;    // dead after k_attn3 -> T2H/T3H (bf16)
  float* QS    = ws + 6*S;    // dead after k_attn3
  float* XP2   = ws + 7*S;    // dead after k_pool -> XSA
  float* XSA   = ws + 7*S;
  float* XCA   = ws + 8*S;
  int*   rpiT  = (int*)(ws + 8*S);   // used only by k_attn3; overwritten by XCA later
  ushort_t* SKIPH = (ushort_t*)(ws + 4*S);
  ushort_t* T1H   = SKIPH + SSLOT;          // second half of slot 4
  ushort_t* T2H   = (ushort_t*)(ws + 5*S);
  ushort_t* T3H   = T2H + SSLOT;            // second half of slot 5
  float* SM  = ws + 9*S;
  float* pooled = SM;          // 4800
  float* KP     = SM + 4800;   // 4800
  float* VP     = SM + 9600;   // 4800
  float* KPN    = SM + 14400;  // 4800
  float* TAB    = SM + 19200;  // 16384
  float* ACA    = SM + 38080;  // 2304
  ushort_t* WB  = (ushort_t*)(SM + 40960);  // 4*248832 bf16 (497664 floats)
  float* BNS    = SM + 40960 + 497664;      // 768 floats
  ushort_t* WQH = (ushort_t*)(BNS + 768);   // 36864 bf16 (18432 f)
  ushort_t* WSH = WQH + 36864;              // 9216 bf16 (4608 f)
  ushort_t* W8H = WSH + 9216;               // 9216 bf16 (4608 f)
  float* PAR    = BNS + 768 + 18432 + 4608 + 4608;  // 8*96*26 floats

  k_prep  <<<3888,  256, 0, stream>>>(w51a, w51b, w52a, w52b, WB);
  k_bnprep<<<1,     384, 0, stream>>>(bn51a, bn51b, bn52a, bn52b, BNS);
  k_prepw <<<144,   256, 0, stream>>>(wqkvv, srw, w8, WQH, WSH, W8H);
  k_rpit  <<<5000,  256, 0, stream>>>(rpi, rpiT);
  k_ln    <<<100,   256, 0, stream>>>(x, nw, nb, XNH);
  k_qkvvm <<<dim3(400,2), 256, 0, stream>>>(XNH, WQH, Q);
  k_qs    <<<400,   256, 0, stream>>>(Q, temp, sls, qe, QN, QS);
  k_srm   <<<400,   256, 0, stream>>>(XNH, WSH, srb, XP2);
  k_pool  <<<4800,  64,  0, stream>>>(XP2, pooled);
  k_lnkv  <<<50,    256, 0, stream>>>(pooled, epaw, epab, wkv, KP, VP);
  k_kpn   <<<1,     256, 0, stream>>>(KP, KPN);
  k_tab   <<<4096,  512, 0, stream>>>(rct, c1w, c1b, c2w, c2b, TAB);
  k_attn3 <<<dim3(100,4), 256, 0, stream>>>(QS, QN, Kb, VSA, KPN, VP, TAB, rpiT,
                                            rbl, ltok, lbias, XSA);
  k_cascore2<<<dim3(96,8), 256, 0, stream>>>(Q, Kb, PAR);
  k_casm2 <<<1,     96,  0, stream>>>(PAR, temp2, ACA);
  k_caout2<<<400,   256, 0, stream>>>(ACA, VCA, XCA);
  k_epa   <<<dim3(100,6),  256, 0, stream>>>(XSA, XCA, x, gamma, o1w, o1b, o2w, o2b,
                                             SKIPF, SKIPH);
  // resblock 1
  k_convm <<<400, 256, 0, stream>>>(SKIPH, WB,        BNS,     nullptr, T1H, nullptr);
  k_convm <<<400, 256, 0, stream>>>(T1H,   WB+WSZ,    BNS+192, SKIPF,   T2H, T2F);
  // resblock 2
  k_convm <<<400, 256, 0, stream>>>(T2H,   WB+2*WSZ,  BNS+384, nullptr, T1H, nullptr);
  k_convm <<<400, 256, 0, stream>>>(T1H,   WB+3*WSZ,  BNS+576, T2F,     T3H, nullptr);
  k_finm  <<<400, 256, 0, stream>>>(SKIPF, T3H, W8H, b8, (float*)d_out);
}